// Round 17
// baseline (172.621 us; speedup 1.0000x reference)
//
#include <hip/hip_runtime.h>
#include <hip/hip_bf16.h>

#define NTOK 4096
#define SCALE 0.17677669529663687f  /* 32^-0.5 */

// 16B-chunk XOR swizzle within a 64B (32-ushort) LDS row.
#define SWZ(r) ((((r) >> 1) ^ ((r) >> 3)) & 3)

using f32x4 = __attribute__((ext_vector_type(4))) float;
using s16x8 = __attribute__((ext_vector_type(8))) short;
using v4i   = __attribute__((ext_vector_type(4))) int;

__device__ __forceinline__ ushort bf_rne(float f) {
  unsigned int u = __builtin_bit_cast(unsigned int, f);
  u += 0x7FFFu + ((u >> 16) & 1u);
  return (ushort)(u >> 16);
}
__device__ __forceinline__ unsigned int pk2(float a, float b) {
  __hip_bfloat162 h = __float22bfloat162_rn(make_float2(a, b));
  unsigned int u;
  __builtin_memcpy(&u, &h, 4);
  return u;
}
__device__ __forceinline__ void gl_lds16(const ushort* g, ushort* l) {
  __builtin_amdgcn_global_load_lds(
      (const __attribute__((address_space(1))) unsigned int*)g,
      (__attribute__((address_space(3))) unsigned int*)l, 16, 0, 0);
}
__device__ __forceinline__ v4i make_srsrc(const void* p) {
  union {
    struct { const void* p; unsigned nr; unsigned fl; } s;
    v4i v;
  } u;
  u.s.p = p;
  u.s.nr = 0xFFFFFFFFu;
  u.s.fl = 0x00020000u;
  return u.v;
}
#if __has_builtin(__builtin_amdgcn_raw_buffer_load_f32)
#define HAVE_RAW_BL 1
#else
#define HAVE_RAW_BL 0
#endif

// ---------------------------------------------------------------------------
// K0: w_qkv (384x256 f32) -> bf16 RNE. grid 96 x 256.
// ---------------------------------------------------------------------------
__global__ __launch_bounds__(256) void k_cvt_w(const float* __restrict__ w,
                                               ushort* __restrict__ wb) {
  const int i = blockIdx.x * 256 + threadIdx.x;
  const float4 v = reinterpret_cast<const float4*>(w)[i];
  ushort4 h;
  h.x = bf_rne(v.x); h.y = bf_rne(v.y); h.z = bf_rne(v.z); h.w = bf_rne(v.w);
  reinterpret_cast<ushort4*>(wb)[i] = h;
}

// ---------------------------------------------------------------------------
// K1 (round-15 structure + depth-2 prefetch + counted-vmcnt raw barriers):
// qkv = w @ x from x f32 [c][n]. 128x128 tile, BK=32, 4 waves, 16 MFMA/iter,
// 16KB LDS single-buffer. Per iter: gl_lds A (issued FIRST), stage B from
// P(it) regs, issue P(it+2) prefetch, then sched_barrier + s_waitcnt
// vmcnt(16) lgkmcnt(0) + raw s_barrier -- the 16 prefetch loads stay in
// flight ACROSS the barrier (T4; __syncthreads would drain them).
// Epilogue: y==0 -> E=exp(q) [c][n] + row sums; y==1 -> softmax-d -> kb;
// y==2 -> vb. grid (32 n, 3 o, 32 b).
// ---------------------------------------------------------------------------
__global__ __launch_bounds__(256) void k_qkv_mfma(const float* __restrict__ x,
                                                  const ushort* __restrict__ wb,
                                                  ushort* __restrict__ Ecn,
                                                  ushort* __restrict__ kb,
                                                  ushort* __restrict__ vb,
                                                  float* __restrict__ spart) {
  const int n0 = blockIdx.x * 128;
  const int o0 = blockIdx.y * 128;
  const int b  = blockIdx.z;
  const float* xb = x + (size_t)b * 256 * NTOK;

  __shared__ ushort As[4096];
  __shared__ ushort Bs[4096];

  const int t = threadIdx.x;
  const int lane = t & 63;
  const int wv = t >> 6;
  const int wr = wv >> 1, wc = wv & 1;
  const int lm = lane & 15;
  const int lk = lane >> 4;

  int aoff[4], boff[4];
#pragma unroll
  for (int mf = 0; mf < 4; ++mf) {
    const int ar = wr * 64 + mf * 16 + lm;
    aoff[mf] = ar * 32 + 8 * (lk ^ SWZ(ar));
  }
#pragma unroll
  for (int nf = 0; nf < 4; ++nf) {
    const int br = wc * 64 + nf * 16 + lm;
    boff[nf] = br * 32 + 8 * (lk ^ SWZ(br));
  }
  const int s1 = t, s2 = t + 256;
  const int r1 = s1 >> 2, q1 = (s1 & 3) ^ SWZ(r1);
  const int r2 = s2 >> 2, q2 = (s2 & 3) ^ SWZ(r2);
  const size_t ga1 = (size_t)(o0 + r1) * 256 + q1 * 8;
  const size_t ga2 = (size_t)(o0 + r2) * 256 + q2 * 8;
  const int lbase1 = wv * 512;
  const int lbase2 = 2048 + wv * 512;
  int sst[2], sn[2], sco[2];
#pragma unroll
  for (int i = 0; i < 2; ++i) {
    const int u = t + 256 * i;
    sn[i] = u & 127;
    sco[i] = u >> 7;
    sst[i] = sn[i] * 32 + 8 * (sco[i] ^ SWZ(sn[i]));
  }
  const float* xbn = xb + n0;
  const v4i rx = make_srsrc(xbn);
  int voff[2];
#pragma unroll
  for (int i = 0; i < 2; ++i) voff[i] = (sco[i] * 8 * NTOK + sn[i]) * 4;

  f32x4 acc[4][4];
#pragma unroll
  for (int i = 0; i < 4; ++i)
#pragma unroll
    for (int j = 0; j < 4; ++j) acc[i][j] = (f32x4){0.f, 0.f, 0.f, 0.f};

#if HAVE_RAW_BL
#define BLOAD(i, j, itc) __builtin_amdgcn_raw_buffer_load_f32(rx, voff[i], (itc) * 524288 + (j) * 16384, 0)
#else
#define BLOAD(i, j, itc) xbn[(size_t)((itc) * 32 + sco[i] * 8 + (j)) * NTOK + sn[i]]
#endif

  // prologue: P(0) -> preA, P(1) -> preB (depth-2 pipeline)
  float preA[16], preB[16];
#pragma unroll
  for (int i = 0; i < 2; ++i)
#pragma unroll
    for (int j = 0; j < 8; ++j) preA[i * 8 + j] = BLOAD(i, j, 0);
#pragma unroll
  for (int i = 0; i < 2; ++i)
#pragma unroll
    for (int j = 0; j < 8; ++j) preB[i * 8 + j] = BLOAD(i, j, 1);

#pragma unroll
  for (int it = 0; it < 8; ++it) {
    const size_t c0 = (size_t)it * 32;
    // ---- A async->LDS FIRST (so vmcnt(16) at the barrier covers them) ----
    gl_lds16(wb + ga1 + c0, As + lbase1);
    gl_lds16(wb + ga2 + c0, As + lbase2);
    // ---- stage B from current pre regs (static selection: it is constant) ----
    float* cur = (it & 1) ? preB : preA;
#pragma unroll
    for (int i = 0; i < 2; ++i) {
      union { s16x8 v; unsigned int u[4]; } pk;
      pk.u[0] = pk2(cur[i * 8 + 0], cur[i * 8 + 1]);
      pk.u[1] = pk2(cur[i * 8 + 2], cur[i * 8 + 3]);
      pk.u[2] = pk2(cur[i * 8 + 4], cur[i * 8 + 5]);
      pk.u[3] = pk2(cur[i * 8 + 6], cur[i * 8 + 7]);
      *reinterpret_cast<s16x8*>(Bs + sst[i]) = pk.v;
    }
    // ---- issue P(it+2) into the just-freed regs ----
    if (it + 2 < 8) {
#pragma unroll
      for (int i = 0; i < 2; ++i)
#pragma unroll
        for (int j = 0; j < 8; ++j) cur[i * 8 + j] = BLOAD(i, j, it + 2);
    }
    // ---- counted-vmcnt barrier: keep the 16 prefetch loads in flight ----
    __builtin_amdgcn_sched_barrier(0);
    if (it + 2 < 8) {
      asm volatile("s_waitcnt vmcnt(16) lgkmcnt(0)" ::: "memory");
    } else {
      asm volatile("s_waitcnt vmcnt(0) lgkmcnt(0)" ::: "memory");
    }
    __builtin_amdgcn_sched_barrier(0);
    __builtin_amdgcn_s_barrier();
    __builtin_amdgcn_sched_barrier(0);
    // ---- MFMA phase ----
    s16x8 af[4], bf[4];
#pragma unroll
    for (int mf = 0; mf < 4; ++mf)
      af[mf] = *reinterpret_cast<const s16x8*>(As + aoff[mf]);
#pragma unroll
    for (int nf = 0; nf < 4; ++nf)
      bf[nf] = *reinterpret_cast<const s16x8*>(Bs + boff[nf]);
#pragma unroll
    for (int mf = 0; mf < 4; ++mf)
#pragma unroll
      for (int nf = 0; nf < 4; ++nf)
        acc[mf][nf] = __builtin_amdgcn_mfma_f32_16x16x32_bf16(af[mf], bf[nf], acc[mf][nf], 0, 0, 0);
    // ---- plain raw barrier before Bs/As overwrite next iter ----
    __builtin_amdgcn_sched_barrier(0);
    __builtin_amdgcn_s_barrier();
    __builtin_amdgcn_sched_barrier(0);
  }
#undef BLOAD

  if (blockIdx.y == 0) {
    // q path: E = exp(q), [c][n] layout + row-sum partials
    ushort* C = Ecn + (size_t)b * 128 * NTOK + n0;
    float* sp = spart + (((size_t)b * 32 + blockIdx.x) * 2 + wc) * 128;
#pragma unroll
    for (int mf = 0; mf < 4; ++mf) {
#pragma unroll
      for (int r = 0; r < 4; ++r) {
        const int ch = wr * 64 + mf * 16 + lk * 4 + r;
        float s = 0.f;
#pragma unroll
        for (int nf = 0; nf < 4; ++nf) {
          const float e = __expf(acc[mf][nf][r]);
          s += e;
          C[(size_t)ch * NTOK + wc * 64 + nf * 16 + lm] = bf_rne(e);
        }
        s += __shfl_xor(s, 1, 64);
        s += __shfl_xor(s, 2, 64);
        s += __shfl_xor(s, 4, 64);
        s += __shfl_xor(s, 8, 64);
        if (lm == 0) sp[ch] = s;
      }
    }
  } else if (blockIdx.y == 1) {
    // k path: softmax over d
#pragma unroll
    for (int nf = 0; nf < 4; ++nf) {
#pragma unroll
      for (int g = 0; g < 2; ++g) {
        float m = -1e30f;
#pragma unroll
        for (int mm = 0; mm < 2; ++mm)
#pragma unroll
          for (int r = 0; r < 4; ++r)
            m = fmaxf(m, acc[g * 2 + mm][nf][r]);
        m = fmaxf(m, __shfl_xor(m, 16, 64));
        m = fmaxf(m, __shfl_xor(m, 32, 64));
        float s = 0.f;
#pragma unroll
        for (int mm = 0; mm < 2; ++mm)
#pragma unroll
          for (int r = 0; r < 4; ++r) {
            const float e = __expf(acc[g * 2 + mm][nf][r] - m);
            acc[g * 2 + mm][nf][r] = e;
            s += e;
          }
        s += __shfl_xor(s, 16, 64);
        s += __shfl_xor(s, 32, 64);
        const float inv = 1.0f / s;
#pragma unroll
        for (int mm = 0; mm < 2; ++mm)
#pragma unroll
          for (int r = 0; r < 4; ++r) acc[g * 2 + mm][nf][r] *= inv;
      }
    }
    ushort* C = kb + (size_t)b * 128 * NTOK + n0;
#pragma unroll
    for (int mf = 0; mf < 4; ++mf) {
      const int row0 = wr * 64 + mf * 16 + lk * 4;
#pragma unroll
      for (int nf = 0; nf < 4; ++nf) {
        const int col = wc * 64 + nf * 16 + lm;
#pragma unroll
        for (int r = 0; r < 4; ++r)
          C[(size_t)(row0 + r) * NTOK + col] = bf_rne(acc[mf][nf][r]);
      }
    }
  } else {
    ushort* C = vb + (size_t)b * 128 * NTOK + n0;
#pragma unroll
    for (int mf = 0; mf < 4; ++mf) {
      const int row0 = wr * 64 + mf * 16 + lk * 4;
#pragma unroll
      for (int nf = 0; nf < 4; ++nf) {
        const int col = wc * 64 + nf * 16 + lm;
#pragma unroll
        for (int r = 0; r < 4; ++r)
          C[(size_t)(row0 + r) * NTOK + col] = bf_rne(acc[mf][nf][r]);
      }
    }
  }
}

// ---------------------------------------------------------------------------
// K2: context partials via bf16 MFMA. grid 256 = bh(128) x half(2);
// 4 waves x 512 tokens each -> 8 segments/bh (full CU coverage).
// ---------------------------------------------------------------------------
__global__ __launch_bounds__(256) void k_context_mfma(const ushort* __restrict__ kb,
                                                      const ushort* __restrict__ vb,
                                                      float* __restrict__ ctx_part) {
  const int bh = blockIdx.x >> 1;
  const int half = blockIdx.x & 1;
  const int w = threadIdx.x >> 6;
  const int seg = half * 4 + w;
  const int lane = threadIdx.x & 63;
  const int lm = lane & 15, lk = lane >> 4;
  const ushort* kp = kb + (size_t)bh * 32 * NTOK + (size_t)seg * 512;
  const ushort* vp = vb + (size_t)bh * 32 * NTOK + (size_t)seg * 512;
  f32x4 acc[2][2];
#pragma unroll
  for (int i = 0; i < 2; ++i)
#pragma unroll
    for (int j = 0; j < 2; ++j) acc[i][j] = (f32x4){0.f, 0.f, 0.f, 0.f};
#pragma unroll 4
  for (int ks = 0; ks < 16; ++ks) {
    const int coff = ks * 32 + lk * 8;
    const s16x8 a0 = *reinterpret_cast<const s16x8*>(kp + (size_t)lm * NTOK + coff);
    const s16x8 a1 = *reinterpret_cast<const s16x8*>(kp + (size_t)(16 + lm) * NTOK + coff);
    const s16x8 b0 = *reinterpret_cast<const s16x8*>(vp + (size_t)lm * NTOK + coff);
    const s16x8 b1 = *reinterpret_cast<const s16x8*>(vp + (size_t)(16 + lm) * NTOK + coff);
    acc[0][0] = __builtin_amdgcn_mfma_f32_16x16x32_bf16(a0, b0, acc[0][0], 0, 0, 0);
    acc[0][1] = __builtin_amdgcn_mfma_f32_16x16x32_bf16(a0, b1, acc[0][1], 0, 0, 0);
    acc[1][0] = __builtin_amdgcn_mfma_f32_16x16x32_bf16(a1, b0, acc[1][0], 0, 0, 0);
    acc[1][1] = __builtin_amdgcn_mfma_f32_16x16x32_bf16(a1, b1, acc[1][1], 0, 0, 0);
  }
  float* op = ctx_part + ((size_t)bh * 8 + seg) * 1024;
#pragma unroll
  for (int et = 0; et < 2; ++et)
#pragma unroll
    for (int dt = 0; dt < 2; ++dt)
#pragma unroll
      for (int r = 0; r < 4; ++r)
        op[(et * 16 + lk * 4 + r) * 32 + dt * 16 + lm] = acc[et][dt][r];
}

// ---------------------------------------------------------------------------
// K5: W2'[b][o][c'] = (sum_d w_out[o][h*32+d] * ctx[b][h][e][d]) * f[c'],
// f[c'] = SCALE / sum_n E[c'][n]. -> bf16. ctx sums 8 segment partials.
// ---------------------------------------------------------------------------
__global__ __launch_bounds__(256) void k_w2(const float* __restrict__ ctx_part,
                                            const float* __restrict__ spart,
                                            const float* __restrict__ w_out,
                                            ushort* __restrict__ W2b) {
  const int b = blockIdx.x;
  const int t = threadIdx.x;
  __shared__ float ctx[4096];
  __shared__ float fbuf[128];
#pragma unroll
  for (int i = 0; i < 16; ++i) {
    const int idx = t + 256 * i;
    const int h = idx >> 10, ed = idx & 1023;
    const float* cp = ctx_part + ((size_t)((b * 4 + h) * 8)) * 1024 + ed;
    float a = 0.f;
#pragma unroll
    for (int j = 0; j < 8; ++j) a += cp[j * 1024];
    ctx[idx] = a;
  }
  if (t < 128) {
    float s = 0.f;
    for (int p = 0; p < 64; ++p) s += spart[((size_t)b * 64 + p) * 128 + t];
    fbuf[t] = SCALE / s;
  }
  __syncthreads();
  const float* wrow = w_out + (size_t)t * 128;
  ushort* wout_row = W2b + ((size_t)b * 256 + t) * 128;
  float wv[32];
  for (int h = 0; h < 4; ++h) {
#pragma unroll
    for (int d = 0; d < 32; ++d) wv[d] = wrow[h * 32 + d];
#pragma unroll 4
    for (int e = 0; e < 32; ++e) {
      float a = 0.f;
#pragma unroll
      for (int d = 0; d < 32; ++d) a += wv[d] * ctx[h * 1024 + e * 32 + d];
      wout_row[h * 32 + e] = bf_rne(a * fbuf[h * 32 + e]);
    }
  }
}

// ---------------------------------------------------------------------------
// K6: out[b][o][n] = sum_c W2'[b][o][c] * E[b][c][n] + b_out[o], bf16 MFMA.
// BK=64, 2 iters. A via gl_lds (swizzled source), B gather staged.
// grid (32, 2, 32).  (at memory roofline: 134 MB fp32 output write)
// ---------------------------------------------------------------------------
__global__ __launch_bounds__(256) void k_out_mfma(const ushort* __restrict__ Ecn,
                                                  const ushort* __restrict__ W2b,
                                                  const float* __restrict__ b_out,
                                                  float* __restrict__ out) {
  const int n0 = blockIdx.x * 128;
  const int o0 = blockIdx.y * 128;
  const int b  = blockIdx.z;
  const ushort* A  = W2b + (size_t)b * 256 * 128;
  const ushort* Bq = Ecn + (size_t)b * 128 * NTOK;

  __shared__ ushort As[8192];
  __shared__ ushort Bt[8192];

  const int t = threadIdx.x;
  const int lane = t & 63;
  const int wv = t >> 6;
  const int wr = wv >> 1, wc = wv & 1;
  const int lm = lane & 15;
  const int lk = lane >> 4;

  int aoff[4][2], boff[4][2];
#pragma unroll
  for (int mf = 0; mf < 4; ++mf) {
    const int ar = wr * 64 + mf * 16 + lm;
#pragma unroll
    for (int ks = 0; ks < 2; ++ks)
      aoff[mf][ks] = ar * 64 + 8 * ((ks * 4 + lk) ^ (ar & 7));
  }
#pragma unroll
  for (int nf = 0; nf < 4; ++nf) {
    const int br = wc * 64 + nf * 16 + lm;
#pragma unroll
    for (int ks = 0; ks < 2; ++ks)
      boff[nf][ks] = br * 64 + 8 * ((ks * 4 + lk) ^ (br & 7));
  }
  size_t gaA[4];
  int lb[4];
#pragma unroll
  for (int i = 0; i < 4; ++i) {
    const int s_total = t + 256 * i;
    const int r = s_total >> 3;
    const int q = (s_total & 7) ^ (r & 7);
    gaA[i] = (size_t)(o0 + r) * 128 + q * 8;
    lb[i] = wv * 512 + i * 2048;
  }
  int bst[8], bn[8], bcg[8];
#pragma unroll
  for (int i = 0; i < 8; ++i) {
    const int u = t + 256 * i;
    bn[i] = u & 127;
    bcg[i] = u >> 7;
    bst[i] = bn[i] * 64 + 8 * ((bcg[i] >> 1) ^ (bn[i] & 7)) + (bcg[i] & 1) * 4;
  }

  f32x4 acc[4][4];
#pragma unroll
  for (int i = 0; i < 4; ++i)
#pragma unroll
    for (int j = 0; j < 4; ++j) acc[i][j] = (f32x4){0.f, 0.f, 0.f, 0.f};

  for (int it = 0; it < 2; ++it) {
    const size_t c0 = (size_t)it * 64;
    __syncthreads();
#pragma unroll
    for (int i = 0; i < 4; ++i)
      gl_lds16(A + gaA[i] + c0, As + lb[i]);
#pragma unroll
    for (int i = 0; i < 8; ++i) {
      const ushort* gp = Bq + (c0 + bcg[i] * 4) * NTOK + n0 + bn[i];
      ushort4 hvec;
      hvec.x = gp[0];
      hvec.y = gp[NTOK];
      hvec.z = gp[2 * NTOK];
      hvec.w = gp[3 * NTOK];
      *reinterpret_cast<ushort4*>(Bt + bst[i]) = hvec;
    }
    __syncthreads();
#pragma unroll
    for (int ks = 0; ks < 2; ++ks) {
      s16x8 af[4], bf[4];
#pragma unroll
      for (int mf = 0; mf < 4; ++mf)
        af[mf] = *reinterpret_cast<const s16x8*>(As + aoff[mf][ks]);
#pragma unroll
      for (int nf = 0; nf < 4; ++nf)
        bf[nf] = *reinterpret_cast<const s16x8*>(Bt + boff[nf][ks]);
#pragma unroll
      for (int mf = 0; mf < 4; ++mf)
#pragma unroll
        for (int nf = 0; nf < 4; ++nf)
          acc[mf][nf] = __builtin_amdgcn_mfma_f32_16x16x32_bf16(af[mf], bf[nf], acc[mf][nf], 0, 0, 0);
    }
  }

  float* C = out + ((size_t)b * 256 + o0) * NTOK + n0;
#pragma unroll
  for (int mf = 0; mf < 4; ++mf) {
    const int row0 = wr * 64 + mf * 16 + lk * 4;
#pragma unroll
    for (int nf = 0; nf < 4; ++nf) {
      const int col = wc * 64 + nf * 16 + lm;
#pragma unroll
      for (int r = 0; r < 4; ++r) {
        const float bias = b_out[o0 + row0 + r];
        C[(size_t)(row0 + r) * NTOK + col] = acc[mf][nf][r] + bias;
      }
    }
  }
}

extern "C" void kernel_launch(void* const* d_in, const int* in_sizes, int n_in,
                              void* d_out, int out_size, void* d_ws, size_t ws_size,
                              hipStream_t stream) {
  const float* x     = (const float*)d_in[0];
  const float* w_qkv = (const float*)d_in[1];
  const float* w_out = (const float*)d_in[2];
  const float* b_out = (const float*)d_in[3];
  float* out = (float*)d_out;

  ushort* kb  = (ushort*)d_ws;                          // 16777216 us (33.5MB)
  ushort* vb  = kb + (size_t)16777216;                  // 33.5MB
  ushort* Ecn = vb + (size_t)16777216;                  // 33.5MB
  float*  ctx_part = (float*)(Ecn + (size_t)16777216);  // 1048576 f32 (4MB)
  float*  spart    = ctx_part + 1048576;                // 262144 f32 (1MB)
  ushort* wb  = (ushort*)(spart + 262144);              // 98304 us
  ushort* W2b = wb + 98304;                             // 1048576 us (2MB)

  k_cvt_w<<<96, 256, 0, stream>>>(w_qkv, wb);
  k_qkv_mfma<<<dim3(32, 3, 32), 256, 0, stream>>>(x, wb, Ecn, kb, vb, spart);
  k_context_mfma<<<256, 256, 0, stream>>>(kb, vb, ctx_part);
  k_w2<<<32, 256, 0, stream>>>(ctx_part, spart, w_out, W2b);
  k_out_mfma<<<dim3(32, 2, 32), 256, 0, stream>>>(Ecn, W2b, b_out, out);
}

// Round 18
// 165.135 us; speedup vs baseline: 1.0453x; 1.0453x over previous
//
#include <hip/hip_runtime.h>
#include <hip/hip_bf16.h>

#define NTOK 4096
#define SCALE 0.17677669529663687f  /* 32^-0.5 */

// 16B-chunk XOR swizzle within a 64B (32-ushort) LDS row (B tile / K6).
#define SWZ(r) ((((r) >> 1) ^ ((r) >> 3)) & 3)

using f32x4 = __attribute__((ext_vector_type(4))) float;
using s16x8 = __attribute__((ext_vector_type(8))) short;
using v4i   = __attribute__((ext_vector_type(4))) int;

__device__ __forceinline__ ushort bf_rne(float f) {
  unsigned int u = __builtin_bit_cast(unsigned int, f);
  u += 0x7FFFu + ((u >> 16) & 1u);
  return (ushort)(u >> 16);
}
__device__ __forceinline__ unsigned int pk2(float a, float b) {
  __hip_bfloat162 h = __float22bfloat162_rn(make_float2(a, b));
  unsigned int u;
  __builtin_memcpy(&u, &h, 4);
  return u;
}
__device__ __forceinline__ void gl_lds16(const ushort* g, ushort* l) {
  __builtin_amdgcn_global_load_lds(
      (const __attribute__((address_space(1))) unsigned int*)g,
      (__attribute__((address_space(3))) unsigned int*)l, 16, 0, 0);
}
__device__ __forceinline__ v4i make_srsrc(const void* p) {
  union {
    struct { const void* p; unsigned nr; unsigned fl; } s;
    v4i v;
  } u;
  u.s.p = p;
  u.s.nr = 0xFFFFFFFFu;
  u.s.fl = 0x00020000u;
  return u.v;
}
#if __has_builtin(__builtin_amdgcn_raw_buffer_load_f32)
#define HAVE_RAW_BL 1
#else
#define HAVE_RAW_BL 0
#endif

// ---------------------------------------------------------------------------
// K0: w_qkv (384x256 f32) -> bf16 RNE. grid 96 x 256.
// ---------------------------------------------------------------------------
__global__ __launch_bounds__(256) void k_cvt_w(const float* __restrict__ w,
                                               ushort* __restrict__ wb) {
  const int i = blockIdx.x * 256 + threadIdx.x;
  const float4 v = reinterpret_cast<const float4*>(w)[i];
  ushort4 h;
  h.x = bf_rne(v.x); h.y = bf_rne(v.y); h.z = bf_rne(v.z); h.w = bf_rne(v.w);
  reinterpret_cast<ushort4*>(wb)[i] = h;
}

// ---------------------------------------------------------------------------
// K1 (A-persistent): qkv = w @ x from x f32 [c][n]. 128x128 tile, BK=32,
// 4 waves, 16 MFMA/iter. A = this o-tile's w (64KB bf16) staged into LDS
// ONCE via gl_lds (5-bit chunk XOR swizzle); NO VMEM waits inside the
// K-loop -- only B's depth-1 reg prefetch, drained at next stage-top after
// a full iteration in flight. LDS 72KB -> 2 blocks/CU (matches observed
// occupancy). Epilogue: y==0 -> E=exp(q) [c][n] + row sums; y==1 ->
// softmax-d -> kb; y==2 -> vb. grid (32 n, 3 o, 32 b).
// ---------------------------------------------------------------------------
__global__ __launch_bounds__(256) void k_qkv_mfma(const float* __restrict__ x,
                                                  const ushort* __restrict__ wb,
                                                  ushort* __restrict__ Ecn,
                                                  ushort* __restrict__ kb,
                                                  ushort* __restrict__ vb,
                                                  float* __restrict__ spart) {
  const int n0 = blockIdx.x * 128;
  const int o0 = blockIdx.y * 128;
  const int b  = blockIdx.z;
  const float* xb = x + (size_t)b * 256 * NTOK;

  __shared__ ushort As[128 * 256];  // 64KB: [o-row][c], 32 chunks/row, ^(row&31)
  __shared__ ushort Bs[4096];       // 8KB per-iter B tile

  const int t = threadIdx.x;
  const int lane = t & 63;
  const int wv = t >> 6;
  const int wr = wv >> 1, wc = wv & 1;
  const int lm = lane & 15;
  const int lk = lane >> 4;

  // B fragment read offsets (swizzled, loop-invariant)
  int boff[4];
#pragma unroll
  for (int nf = 0; nf < 4; ++nf) {
    const int br = wc * 64 + nf * 16 + lm;
    boff[nf] = br * 32 + 8 * (lk ^ SWZ(br));
  }
  // A fragment rows (chunk index recomputed per iter: (it*4+lk) ^ (ar&31))
  int arow[4];
#pragma unroll
  for (int mf = 0; mf < 4; ++mf) arow[mf] = wr * 64 + mf * 16 + lm;

  // B staging: unit u = t + 256*i -> (n = u&127, c-oct = u>>7)
  int sst[2], sn[2], sco[2];
#pragma unroll
  for (int i = 0; i < 2; ++i) {
    const int u = t + 256 * i;
    sn[i] = u & 127;
    sco[i] = u >> 7;
    sst[i] = sn[i] * 32 + 8 * (sco[i] ^ SWZ(sn[i]));
  }
  const float* xbn = xb + n0;
  const v4i rx = make_srsrc(xbn);
  int voff[2];
#pragma unroll
  for (int i = 0; i < 2; ++i) voff[i] = (sco[i] * 8 * NTOK + sn[i]) * 4;

#if HAVE_RAW_BL
#define BLOAD(i, j, itc) __builtin_amdgcn_raw_buffer_load_f32(rx, voff[i], (itc) * 524288 + (j) * 16384, 0)
#else
#define BLOAD(i, j, itc) xbn[(size_t)((itc) * 32 + sco[i] * 8 + (j)) * NTOK + sn[i]]
#endif

  // ---- prologue: stage ALL of A (64KB) once; issue B P(0); one drain ----
  {
    // chunk s = i*256 + t; row = s>>5, slot = s&31; global q = slot ^ (row&31)
#pragma unroll
    for (int i = 0; i < 16; ++i) {
      const int s = i * 256 + t;
      const int row = s >> 5;
      const int q = (s & 31) ^ (row & 31);
      gl_lds16(wb + (size_t)(o0 + row) * 256 + q * 8,
               As + (size_t)(i * 256 + wv * 64) * 8);
    }
  }
  float pre[16];
#pragma unroll
  for (int i = 0; i < 2; ++i)
#pragma unroll
    for (int j = 0; j < 8; ++j) pre[i * 8 + j] = BLOAD(i, j, 0);
  __syncthreads();  // drains A gl_lds + P(0); one-time cost

  f32x4 acc[4][4];
#pragma unroll
  for (int i = 0; i < 4; ++i)
#pragma unroll
    for (int j = 0; j < 4; ++j) acc[i][j] = (f32x4){0.f, 0.f, 0.f, 0.f};

#pragma unroll
  for (int it = 0; it < 8; ++it) {
    // ---- P(it) already landed (it=0: prologue drain; else vmcnt below) ----
    if (it > 0) {
      __builtin_amdgcn_sched_barrier(0);
      asm volatile("s_waitcnt vmcnt(0)" ::: "memory");
      __builtin_amdgcn_sched_barrier(0);
    }
    // ---- stage B from pre regs ----
#pragma unroll
    for (int i = 0; i < 2; ++i) {
      union { s16x8 v; unsigned int u[4]; } pk;
      pk.u[0] = pk2(pre[i * 8 + 0], pre[i * 8 + 1]);
      pk.u[1] = pk2(pre[i * 8 + 2], pre[i * 8 + 3]);
      pk.u[2] = pk2(pre[i * 8 + 4], pre[i * 8 + 5]);
      pk.u[3] = pk2(pre[i * 8 + 6], pre[i * 8 + 7]);
      *reinterpret_cast<s16x8*>(Bs + sst[i]) = pk.v;
    }
    // ---- issue P(it+1): a full iteration of latency cover ----
    if (it < 7) {
#pragma unroll
      for (int i = 0; i < 2; ++i)
#pragma unroll
        for (int j = 0; j < 8; ++j) pre[i * 8 + j] = BLOAD(i, j, it + 1);
    }
    // ---- Bs visible to all waves (prefetch stays in flight) ----
    __builtin_amdgcn_sched_barrier(0);
    asm volatile("s_waitcnt lgkmcnt(0)" ::: "memory");
    __builtin_amdgcn_sched_barrier(0);
    __builtin_amdgcn_s_barrier();
    __builtin_amdgcn_sched_barrier(0);
    // ---- MFMA phase: pure LDS->reg->MFMA ----
    s16x8 af[4], bf[4];
#pragma unroll
    for (int mf = 0; mf < 4; ++mf) {
      const int sc = (it * 4 + lk) ^ (arow[mf] & 31);
      af[mf] = *reinterpret_cast<const s16x8*>(As + arow[mf] * 256 + 8 * sc);
    }
#pragma unroll
    for (int nf = 0; nf < 4; ++nf)
      bf[nf] = *reinterpret_cast<const s16x8*>(Bs + boff[nf]);
#pragma unroll
    for (int mf = 0; mf < 4; ++mf)
#pragma unroll
      for (int nf = 0; nf < 4; ++nf)
        acc[mf][nf] = __builtin_amdgcn_mfma_f32_16x16x32_bf16(af[mf], bf[nf], acc[mf][nf], 0, 0, 0);
    // ---- protect Bs before next iter's overwrite ----
    __builtin_amdgcn_sched_barrier(0);
    __builtin_amdgcn_s_barrier();
    __builtin_amdgcn_sched_barrier(0);
  }
#undef BLOAD

  if (blockIdx.y == 0) {
    // q path: E = exp(q), [c][n] layout + row-sum partials
    ushort* C = Ecn + (size_t)b * 128 * NTOK + n0;
    float* sp = spart + (((size_t)b * 32 + blockIdx.x) * 2 + wc) * 128;
#pragma unroll
    for (int mf = 0; mf < 4; ++mf) {
#pragma unroll
      for (int r = 0; r < 4; ++r) {
        const int ch = wr * 64 + mf * 16 + lk * 4 + r;
        float s = 0.f;
#pragma unroll
        for (int nf = 0; nf < 4; ++nf) {
          const float e = __expf(acc[mf][nf][r]);
          s += e;
          C[(size_t)ch * NTOK + wc * 64 + nf * 16 + lm] = bf_rne(e);
        }
        s += __shfl_xor(s, 1, 64);
        s += __shfl_xor(s, 2, 64);
        s += __shfl_xor(s, 4, 64);
        s += __shfl_xor(s, 8, 64);
        if (lm == 0) sp[ch] = s;
      }
    }
  } else if (blockIdx.y == 1) {
    // k path: softmax over d
#pragma unroll
    for (int nf = 0; nf < 4; ++nf) {
#pragma unroll
      for (int g = 0; g < 2; ++g) {
        float m = -1e30f;
#pragma unroll
        for (int mm = 0; mm < 2; ++mm)
#pragma unroll
          for (int r = 0; r < 4; ++r)
            m = fmaxf(m, acc[g * 2 + mm][nf][r]);
        m = fmaxf(m, __shfl_xor(m, 16, 64));
        m = fmaxf(m, __shfl_xor(m, 32, 64));
        float s = 0.f;
#pragma unroll
        for (int mm = 0; mm < 2; ++mm)
#pragma unroll
          for (int r = 0; r < 4; ++r) {
            const float e = __expf(acc[g * 2 + mm][nf][r] - m);
            acc[g * 2 + mm][nf][r] = e;
            s += e;
          }
        s += __shfl_xor(s, 16, 64);
        s += __shfl_xor(s, 32, 64);
        const float inv = 1.0f / s;
#pragma unroll
        for (int mm = 0; mm < 2; ++mm)
#pragma unroll
          for (int r = 0; r < 4; ++r) acc[g * 2 + mm][nf][r] *= inv;
      }
    }
    ushort* C = kb + (size_t)b * 128 * NTOK + n0;
#pragma unroll
    for (int mf = 0; mf < 4; ++mf) {
      const int row0 = wr * 64 + mf * 16 + lk * 4;
#pragma unroll
      for (int nf = 0; nf < 4; ++nf) {
        const int col = wc * 64 + nf * 16 + lm;
#pragma unroll
        for (int r = 0; r < 4; ++r)
          C[(size_t)(row0 + r) * NTOK + col] = bf_rne(acc[mf][nf][r]);
      }
    }
  } else {
    ushort* C = vb + (size_t)b * 128 * NTOK + n0;
#pragma unroll
    for (int mf = 0; mf < 4; ++mf) {
      const int row0 = wr * 64 + mf * 16 + lk * 4;
#pragma unroll
      for (int nf = 0; nf < 4; ++nf) {
        const int col = wc * 64 + nf * 16 + lm;
#pragma unroll
        for (int r = 0; r < 4; ++r)
          C[(size_t)(row0 + r) * NTOK + col] = bf_rne(acc[mf][nf][r]);
      }
    }
  }
}

// ---------------------------------------------------------------------------
// K2: context partials via bf16 MFMA. grid 256 = bh(128) x half(2);
// 4 waves x 512 tokens each -> 8 segments/bh (full CU coverage).
// ---------------------------------------------------------------------------
__global__ __launch_bounds__(256) void k_context_mfma(const ushort* __restrict__ kb,
                                                      const ushort* __restrict__ vb,
                                                      float* __restrict__ ctx_part) {
  const int bh = blockIdx.x >> 1;
  const int half = blockIdx.x & 1;
  const int w = threadIdx.x >> 6;
  const int seg = half * 4 + w;
  const int lane = threadIdx.x & 63;
  const int lm = lane & 15, lk = lane >> 4;
  const ushort* kp = kb + (size_t)bh * 32 * NTOK + (size_t)seg * 512;
  const ushort* vp = vb + (size_t)bh * 32 * NTOK + (size_t)seg * 512;
  f32x4 acc[2][2];
#pragma unroll
  for (int i = 0; i < 2; ++i)
#pragma unroll
    for (int j = 0; j < 2; ++j) acc[i][j] = (f32x4){0.f, 0.f, 0.f, 0.f};
#pragma unroll 4
  for (int ks = 0; ks < 16; ++ks) {
    const int coff = ks * 32 + lk * 8;
    const s16x8 a0 = *reinterpret_cast<const s16x8*>(kp + (size_t)lm * NTOK + coff);
    const s16x8 a1 = *reinterpret_cast<const s16x8*>(kp + (size_t)(16 + lm) * NTOK + coff);
    const s16x8 b0 = *reinterpret_cast<const s16x8*>(vp + (size_t)lm * NTOK + coff);
    const s16x8 b1 = *reinterpret_cast<const s16x8*>(vp + (size_t)(16 + lm) * NTOK + coff);
    acc[0][0] = __builtin_amdgcn_mfma_f32_16x16x32_bf16(a0, b0, acc[0][0], 0, 0, 0);
    acc[0][1] = __builtin_amdgcn_mfma_f32_16x16x32_bf16(a0, b1, acc[0][1], 0, 0, 0);
    acc[1][0] = __builtin_amdgcn_mfma_f32_16x16x32_bf16(a1, b0, acc[1][0], 0, 0, 0);
    acc[1][1] = __builtin_amdgcn_mfma_f32_16x16x32_bf16(a1, b1, acc[1][1], 0, 0, 0);
  }
  float* op = ctx_part + ((size_t)bh * 8 + seg) * 1024;
#pragma unroll
  for (int et = 0; et < 2; ++et)
#pragma unroll
    for (int dt = 0; dt < 2; ++dt)
#pragma unroll
      for (int r = 0; r < 4; ++r)
        op[(et * 16 + lk * 4 + r) * 32 + dt * 16 + lm] = acc[et][dt][r];
}

// ---------------------------------------------------------------------------
// K5: W2'[b][o][c'] = (sum_d w_out[o][h*32+d] * ctx[b][h][e][d]) * f[c'],
// f[c'] = SCALE / sum_n E[c'][n]. -> bf16. ctx sums 8 segment partials.
// ---------------------------------------------------------------------------
__global__ __launch_bounds__(256) void k_w2(const float* __restrict__ ctx_part,
                                            const float* __restrict__ spart,
                                            const float* __restrict__ w_out,
                                            ushort* __restrict__ W2b) {
  const int b = blockIdx.x;
  const int t = threadIdx.x;
  __shared__ float ctx[4096];
  __shared__ float fbuf[128];
#pragma unroll
  for (int i = 0; i < 16; ++i) {
    const int idx = t + 256 * i;
    const int h = idx >> 10, ed = idx & 1023;
    const float* cp = ctx_part + ((size_t)((b * 4 + h) * 8)) * 1024 + ed;
    float a = 0.f;
#pragma unroll
    for (int j = 0; j < 8; ++j) a += cp[j * 1024];
    ctx[idx] = a;
  }
  if (t < 128) {
    float s = 0.f;
    for (int p = 0; p < 64; ++p) s += spart[((size_t)b * 64 + p) * 128 + t];
    fbuf[t] = SCALE / s;
  }
  __syncthreads();
  const float* wrow = w_out + (size_t)t * 128;
  ushort* wout_row = W2b + ((size_t)b * 256 + t) * 128;
  float wv[32];
  for (int h = 0; h < 4; ++h) {
#pragma unroll
    for (int d = 0; d < 32; ++d) wv[d] = wrow[h * 32 + d];
#pragma unroll 4
    for (int e = 0; e < 32; ++e) {
      float a = 0.f;
#pragma unroll
      for (int d = 0; d < 32; ++d) a += wv[d] * ctx[h * 1024 + e * 32 + d];
      wout_row[h * 32 + e] = bf_rne(a * fbuf[h * 32 + e]);
    }
  }
}

// ---------------------------------------------------------------------------
// K6: out[b][o][n] = sum_c W2'[b][o][c] * E[b][c][n] + b_out[o], bf16 MFMA.
// BK=64, 2 iters. A via gl_lds (swizzled source), B gather staged.
// grid (32, 2, 32).  (at memory roofline: 134 MB fp32 output write)
// ---------------------------------------------------------------------------
__global__ __launch_bounds__(256) void k_out_mfma(const ushort* __restrict__ Ecn,
                                                  const ushort* __restrict__ W2b,
                                                  const float* __restrict__ b_out,
                                                  float* __restrict__ out) {
  const int n0 = blockIdx.x * 128;
  const int o0 = blockIdx.y * 128;
  const int b  = blockIdx.z;
  const ushort* A  = W2b + (size_t)b * 256 * 128;
  const ushort* Bq = Ecn + (size_t)b * 128 * NTOK;

  __shared__ ushort As[8192];
  __shared__ ushort Bt[8192];

  const int t = threadIdx.x;
  const int lane = t & 63;
  const int wv = t >> 6;
  const int wr = wv >> 1, wc = wv & 1;
  const int lm = lane & 15;
  const int lk = lane >> 4;

  int aoff[4][2], boff[4][2];
#pragma unroll
  for (int mf = 0; mf < 4; ++mf) {
    const int ar = wr * 64 + mf * 16 + lm;
#pragma unroll
    for (int ks = 0; ks < 2; ++ks)
      aoff[mf][ks] = ar * 64 + 8 * ((ks * 4 + lk) ^ (ar & 7));
  }
#pragma unroll
  for (int nf = 0; nf < 4; ++nf) {
    const int br = wc * 64 + nf * 16 + lm;
#pragma unroll
    for (int ks = 0; ks < 2; ++ks)
      boff[nf][ks] = br * 64 + 8 * ((ks * 4 + lk) ^ (br & 7));
  }
  size_t gaA[4];
  int lb[4];
#pragma unroll
  for (int i = 0; i < 4; ++i) {
    const int s_total = t + 256 * i;
    const int r = s_total >> 3;
    const int q = (s_total & 7) ^ (r & 7);
    gaA[i] = (size_t)(o0 + r) * 128 + q * 8;
    lb[i] = wv * 512 + i * 2048;
  }
  int bst[8], bn[8], bcg[8];
#pragma unroll
  for (int i = 0; i < 8; ++i) {
    const int u = t + 256 * i;
    bn[i] = u & 127;
    bcg[i] = u >> 7;
    bst[i] = bn[i] * 64 + 8 * ((bcg[i] >> 1) ^ (bn[i] & 7)) + (bcg[i] & 1) * 4;
  }

  f32x4 acc[4][4];
#pragma unroll
  for (int i = 0; i < 4; ++i)
#pragma unroll
    for (int j = 0; j < 4; ++j) acc[i][j] = (f32x4){0.f, 0.f, 0.f, 0.f};

  for (int it = 0; it < 2; ++it) {
    const size_t c0 = (size_t)it * 64;
    __syncthreads();
#pragma unroll
    for (int i = 0; i < 4; ++i)
      gl_lds16(A + gaA[i] + c0, As + lb[i]);
#pragma unroll
    for (int i = 0; i < 8; ++i) {
      const ushort* gp = Bq + (c0 + bcg[i] * 4) * NTOK + n0 + bn[i];
      ushort4 hvec;
      hvec.x = gp[0];
      hvec.y = gp[NTOK];
      hvec.z = gp[2 * NTOK];
      hvec.w = gp[3 * NTOK];
      *reinterpret_cast<ushort4*>(Bt + bst[i]) = hvec;
    }
    __syncthreads();
#pragma unroll
    for (int ks = 0; ks < 2; ++ks) {
      s16x8 af[4], bf[4];
#pragma unroll
      for (int mf = 0; mf < 4; ++mf)
        af[mf] = *reinterpret_cast<const s16x8*>(As + aoff[mf][ks]);
#pragma unroll
      for (int nf = 0; nf < 4; ++nf)
        bf[nf] = *reinterpret_cast<const s16x8*>(Bt + boff[nf][ks]);
#pragma unroll
      for (int mf = 0; mf < 4; ++mf)
#pragma unroll
        for (int nf = 0; nf < 4; ++nf)
          acc[mf][nf] = __builtin_amdgcn_mfma_f32_16x16x32_bf16(af[mf], bf[nf], acc[mf][nf], 0, 0, 0);
    }
  }

  float* C = out + ((size_t)b * 256 + o0) * NTOK + n0;
#pragma unroll
  for (int mf = 0; mf < 4; ++mf) {
    const int row0 = wr * 64 + mf * 16 + lk * 4;
#pragma unroll
    for (int nf = 0; nf < 4; ++nf) {
      const int col = wc * 64 + nf * 16 + lm;
#pragma unroll
      for (int r = 0; r < 4; ++r) {
        const float bias = b_out[o0 + row0 + r];
        C[(size_t)(row0 + r) * NTOK + col] = acc[mf][nf][r] + bias;
      }
    }
  }
}

extern "C" void kernel_launch(void* const* d_in, const int* in_sizes, int n_in,
                              void* d_out, int out_size, void* d_ws, size_t ws_size,
                              hipStream_t stream) {
  const float* x     = (const float*)d_in[0];
  const float* w_qkv = (const float*)d_in[1];
  const float* w_out = (const float*)d_in[2];
  const float* b_out = (const float*)d_in[3];
  float* out = (float*)d_out;

  ushort* kb  = (ushort*)d_ws;                          // 16777216 us (33.5MB)
  ushort* vb  = kb + (size_t)16777216;                  // 33.5MB
  ushort* Ecn = vb + (size_t)16777216;                  // 33.5MB
  float*  ctx_part = (float*)(Ecn + (size_t)16777216);  // 1048576 f32 (4MB)
  float*  spart    = ctx_part + 1048576;                // 262144 f32 (1MB)
  ushort* wb  = (ushort*)(spart + 262144);              // 98304 us
  ushort* W2b = wb + 98304;                             // 1048576 us (2MB)

  k_cvt_w<<<96, 256, 0, stream>>>(w_qkv, wb);
  k_qkv_mfma<<<dim3(32, 3, 32), 256, 0, stream>>>(x, wb, Ecn, kb, vb, spart);
  k_context_mfma<<<256, 256, 0, stream>>>(kb, vb, ctx_part);
  k_w2<<<32, 256, 0, stream>>>(ctx_part, spart, w_out, W2b);
  k_out_mfma<<<dim3(32, 2, 32), 256, 0, stream>>>(Ecn, W2b, b_out, out);
}

// Round 19
// 160.400 us; speedup vs baseline: 1.0762x; 1.0295x over previous
//
#include <hip/hip_runtime.h>
#include <hip/hip_bf16.h>

#define NTOK 4096
#define SCALE 0.17677669529663687f  /* 32^-0.5 */

// 16B-chunk XOR swizzle within a 64B (32-ushort) LDS row (K6 tiles).
#define SWZ(r) ((((r) >> 1) ^ ((r) >> 3)) & 3)

using f32x4 = __attribute__((ext_vector_type(4))) float;
using s16x8 = __attribute__((ext_vector_type(8))) short;
using v4i   = __attribute__((ext_vector_type(4))) int;

__device__ __forceinline__ ushort bf_rne(float f) {
  unsigned int u = __builtin_bit_cast(unsigned int, f);
  u += 0x7FFFu + ((u >> 16) & 1u);
  return (ushort)(u >> 16);
}
__device__ __forceinline__ unsigned int pk2(float a, float b) {
  __hip_bfloat162 h = __float22bfloat162_rn(make_float2(a, b));
  unsigned int u;
  __builtin_memcpy(&u, &h, 4);
  return u;
}
__device__ __forceinline__ void gl_lds16(const ushort* g, ushort* l) {
  __builtin_amdgcn_global_load_lds(
      (const __attribute__((address_space(1))) unsigned int*)g,
      (__attribute__((address_space(3))) unsigned int*)l, 16, 0, 0);
}
__device__ __forceinline__ v4i make_srsrc(const void* p) {
  union {
    struct { const void* p; unsigned nr; unsigned fl; } s;
    v4i v;
  } u;
  u.s.p = p;
  u.s.nr = 0xFFFFFFFFu;
  u.s.fl = 0x00020000u;
  return u.v;
}
#if __has_builtin(__builtin_amdgcn_raw_buffer_load_f32)
#define HAVE_RAW_BL 1
#else
#define HAVE_RAW_BL 0
#endif

// ---------------------------------------------------------------------------
// K0: w_qkv (384x256 f32) -> bf16 RNE. grid 96 x 256.
// ---------------------------------------------------------------------------
__global__ __launch_bounds__(256) void k_cvt_w(const float* __restrict__ w,
                                               ushort* __restrict__ wb) {
  const int i = blockIdx.x * 256 + threadIdx.x;
  const float4 v = reinterpret_cast<const float4*>(w)[i];
  ushort4 h;
  h.x = bf_rne(v.x); h.y = bf_rne(v.y); h.z = bf_rne(v.z); h.w = bf_rne(v.w);
  reinterpret_cast<ushort4*>(wb)[i] = h;
}

// ---------------------------------------------------------------------------
// K1 (A-persistent + BK=64): qkv = w @ x from x f32 [c][n]. 128x128 tile,
// 4 waves, A (64KB bf16) in LDS once; B tile 64c x 128n (16KB) reg-staged
// with depth-1 prefetch; 4 iters x 32 MFMA, 2 barriers/iter (16 sync events
// vs 32 at BK=32). setprio(1) around the MFMA cluster. LDS 80KB -> 2
// blocks/CU. Epilogue: y==0 -> E=exp(q) [c][n] + row sums; y==1 ->
// softmax-d -> kb; y==2 -> vb. grid (32 n, 3 o, 32 b).
// ---------------------------------------------------------------------------
__global__ __launch_bounds__(256) void k_qkv_mfma(const float* __restrict__ x,
                                                  const ushort* __restrict__ wb,
                                                  ushort* __restrict__ Ecn,
                                                  ushort* __restrict__ kb,
                                                  ushort* __restrict__ vb,
                                                  float* __restrict__ spart) {
  const int n0 = blockIdx.x * 128;
  const int o0 = blockIdx.y * 128;
  const int b  = blockIdx.z;
  const float* xb = x + (size_t)b * 256 * NTOK;

  __shared__ ushort As[128 * 256];  // 64KB: [o-row][c], 32 chunks/row, ^(row&31)
  __shared__ ushort Bs[128 * 64];   // 16KB: [n][64c], 8 chunks/row, ^(n&7)

  const int t = threadIdx.x;
  const int lane = t & 63;
  const int wv = t >> 6;
  const int wr = wv >> 1, wc = wv & 1;
  const int lm = lane & 15;
  const int lk = lane >> 4;

  // B fragment rows (loop-invariant)
  int brow[4];
#pragma unroll
  for (int nf = 0; nf < 4; ++nf) brow[nf] = wc * 64 + nf * 16 + lm;
  // A fragment rows
  int arow[4];
#pragma unroll
  for (int mf = 0; mf < 4; ++mf) arow[mf] = wr * 64 + mf * 16 + lm;

  // B staging: unit u = t + 256*i (i<4) -> (n = u&127, c-oct = u>>7, 0..7)
  int sst[4], sn[4], sco[4];
#pragma unroll
  for (int i = 0; i < 4; ++i) {
    const int u = t + 256 * i;
    sn[i] = u & 127;
    sco[i] = u >> 7;
    sst[i] = sn[i] * 64 + 8 * (sco[i] ^ (sn[i] & 7));
  }
  const float* xbn = xb + n0;
  const v4i rx = make_srsrc(xbn);
  int voff[4];
#pragma unroll
  for (int i = 0; i < 4; ++i) voff[i] = (sco[i] * 8 * NTOK + sn[i]) * 4;

#if HAVE_RAW_BL
#define BLOAD(i, j, itc) __builtin_amdgcn_raw_buffer_load_f32(rx, voff[i], (itc) * 1048576 + (j) * 16384, 0)
#else
#define BLOAD(i, j, itc) xbn[(size_t)((itc) * 64 + sco[i] * 8 + (j)) * NTOK + sn[i]]
#endif

  // ---- prologue: stage ALL of A once; issue B P(0); one drain ----
#pragma unroll
  for (int i = 0; i < 16; ++i) {
    const int s = i * 256 + t;
    const int row = s >> 5;
    const int q = (s & 31) ^ (row & 31);
    gl_lds16(wb + (size_t)(o0 + row) * 256 + q * 8,
             As + (size_t)(i * 256 + wv * 64) * 8);
  }
  float pre[32];
#pragma unroll
  for (int i = 0; i < 4; ++i)
#pragma unroll
    for (int j = 0; j < 8; ++j) pre[i * 8 + j] = BLOAD(i, j, 0);
  __syncthreads();  // drains A gl_lds + P(0); one-time cost

  f32x4 acc[4][4];
#pragma unroll
  for (int i = 0; i < 4; ++i)
#pragma unroll
    for (int j = 0; j < 4; ++j) acc[i][j] = (f32x4){0.f, 0.f, 0.f, 0.f};

#pragma unroll
  for (int it = 0; it < 4; ++it) {
    // ---- P(it) landed (it=0: prologue; else counted wait below) ----
    if (it > 0) {
      __builtin_amdgcn_sched_barrier(0);
      asm volatile("s_waitcnt vmcnt(0)" ::: "memory");
      __builtin_amdgcn_sched_barrier(0);
    }
    // ---- stage B from pre regs (4x b128 writes) ----
#pragma unroll
    for (int i = 0; i < 4; ++i) {
      union { s16x8 v; unsigned int u[4]; } pk;
      pk.u[0] = pk2(pre[i * 8 + 0], pre[i * 8 + 1]);
      pk.u[1] = pk2(pre[i * 8 + 2], pre[i * 8 + 3]);
      pk.u[2] = pk2(pre[i * 8 + 4], pre[i * 8 + 5]);
      pk.u[3] = pk2(pre[i * 8 + 6], pre[i * 8 + 7]);
      *reinterpret_cast<s16x8*>(Bs + sst[i]) = pk.v;
    }
    // ---- issue P(it+1): full iteration of latency cover ----
    if (it < 3) {
#pragma unroll
      for (int i = 0; i < 4; ++i)
#pragma unroll
        for (int j = 0; j < 8; ++j) pre[i * 8 + j] = BLOAD(i, j, it + 1);
    }
    // ---- Bs visible to all waves (prefetch stays in flight) ----
    __builtin_amdgcn_sched_barrier(0);
    asm volatile("s_waitcnt lgkmcnt(0)" ::: "memory");
    __builtin_amdgcn_sched_barrier(0);
    __builtin_amdgcn_s_barrier();
    __builtin_amdgcn_sched_barrier(0);
    // ---- MFMA phase: 2 k-slices x 16 MFMA, pure LDS->reg->MFMA ----
    __builtin_amdgcn_s_setprio(1);
#pragma unroll
    for (int ks = 0; ks < 2; ++ks) {
      s16x8 af[4], bf[4];
#pragma unroll
      for (int mf = 0; mf < 4; ++mf) {
        const int sc = (it * 8 + ks * 4 + lk) ^ (arow[mf] & 31);
        af[mf] = *reinterpret_cast<const s16x8*>(As + arow[mf] * 256 + 8 * sc);
      }
#pragma unroll
      for (int nf = 0; nf < 4; ++nf) {
        const int bc = (ks * 4 + lk) ^ (brow[nf] & 7);
        bf[nf] = *reinterpret_cast<const s16x8*>(Bs + brow[nf] * 64 + 8 * bc);
      }
#pragma unroll
      for (int mf = 0; mf < 4; ++mf)
#pragma unroll
        for (int nf = 0; nf < 4; ++nf)
          acc[mf][nf] = __builtin_amdgcn_mfma_f32_16x16x32_bf16(af[mf], bf[nf], acc[mf][nf], 0, 0, 0);
    }
    __builtin_amdgcn_s_setprio(0);
    // ---- protect Bs before next iter's overwrite ----
    __builtin_amdgcn_sched_barrier(0);
    __builtin_amdgcn_s_barrier();
    __builtin_amdgcn_sched_barrier(0);
  }
#undef BLOAD

  if (blockIdx.y == 0) {
    // q path: E = exp(q), [c][n] layout + row-sum partials
    ushort* C = Ecn + (size_t)b * 128 * NTOK + n0;
    float* sp = spart + (((size_t)b * 32 + blockIdx.x) * 2 + wc) * 128;
#pragma unroll
    for (int mf = 0; mf < 4; ++mf) {
#pragma unroll
      for (int r = 0; r < 4; ++r) {
        const int ch = wr * 64 + mf * 16 + lk * 4 + r;
        float s = 0.f;
#pragma unroll
        for (int nf = 0; nf < 4; ++nf) {
          const float e = __expf(acc[mf][nf][r]);
          s += e;
          C[(size_t)ch * NTOK + wc * 64 + nf * 16 + lm] = bf_rne(e);
        }
        s += __shfl_xor(s, 1, 64);
        s += __shfl_xor(s, 2, 64);
        s += __shfl_xor(s, 4, 64);
        s += __shfl_xor(s, 8, 64);
        if (lm == 0) sp[ch] = s;
      }
    }
  } else if (blockIdx.y == 1) {
    // k path: softmax over d
#pragma unroll
    for (int nf = 0; nf < 4; ++nf) {
#pragma unroll
      for (int g = 0; g < 2; ++g) {
        float m = -1e30f;
#pragma unroll
        for (int mm = 0; mm < 2; ++mm)
#pragma unroll
          for (int r = 0; r < 4; ++r)
            m = fmaxf(m, acc[g * 2 + mm][nf][r]);
        m = fmaxf(m, __shfl_xor(m, 16, 64));
        m = fmaxf(m, __shfl_xor(m, 32, 64));
        float s = 0.f;
#pragma unroll
        for (int mm = 0; mm < 2; ++mm)
#pragma unroll
          for (int r = 0; r < 4; ++r) {
            const float e = __expf(acc[g * 2 + mm][nf][r] - m);
            acc[g * 2 + mm][nf][r] = e;
            s += e;
          }
        s += __shfl_xor(s, 16, 64);
        s += __shfl_xor(s, 32, 64);
        const float inv = 1.0f / s;
#pragma unroll
        for (int mm = 0; mm < 2; ++mm)
#pragma unroll
          for (int r = 0; r < 4; ++r) acc[g * 2 + mm][nf][r] *= inv;
      }
    }
    ushort* C = kb + (size_t)b * 128 * NTOK + n0;
#pragma unroll
    for (int mf = 0; mf < 4; ++mf) {
      const int row0 = wr * 64 + mf * 16 + lk * 4;
#pragma unroll
      for (int nf = 0; nf < 4; ++nf) {
        const int col = wc * 64 + nf * 16 + lm;
#pragma unroll
        for (int r = 0; r < 4; ++r)
          C[(size_t)(row0 + r) * NTOK + col] = bf_rne(acc[mf][nf][r]);
      }
    }
  } else {
    ushort* C = vb + (size_t)b * 128 * NTOK + n0;
#pragma unroll
    for (int mf = 0; mf < 4; ++mf) {
      const int row0 = wr * 64 + mf * 16 + lk * 4;
#pragma unroll
      for (int nf = 0; nf < 4; ++nf) {
        const int col = wc * 64 + nf * 16 + lm;
#pragma unroll
        for (int r = 0; r < 4; ++r)
          C[(size_t)(row0 + r) * NTOK + col] = bf_rne(acc[mf][nf][r]);
      }
    }
  }
}

// ---------------------------------------------------------------------------
// K2: context partials via bf16 MFMA. grid 256 = bh(128) x half(2);
// 4 waves x 512 tokens each -> 8 segments/bh (full CU coverage).
// ---------------------------------------------------------------------------
__global__ __launch_bounds__(256) void k_context_mfma(const ushort* __restrict__ kb,
                                                      const ushort* __restrict__ vb,
                                                      float* __restrict__ ctx_part) {
  const int bh = blockIdx.x >> 1;
  const int half = blockIdx.x & 1;
  const int w = threadIdx.x >> 6;
  const int seg = half * 4 + w;
  const int lane = threadIdx.x & 63;
  const int lm = lane & 15, lk = lane >> 4;
  const ushort* kp = kb + (size_t)bh * 32 * NTOK + (size_t)seg * 512;
  const ushort* vp = vb + (size_t)bh * 32 * NTOK + (size_t)seg * 512;
  f32x4 acc[2][2];
#pragma unroll
  for (int i = 0; i < 2; ++i)
#pragma unroll
    for (int j = 0; j < 2; ++j) acc[i][j] = (f32x4){0.f, 0.f, 0.f, 0.f};
#pragma unroll 4
  for (int ks = 0; ks < 16; ++ks) {
    const int coff = ks * 32 + lk * 8;
    const s16x8 a0 = *reinterpret_cast<const s16x8*>(kp + (size_t)lm * NTOK + coff);
    const s16x8 a1 = *reinterpret_cast<const s16x8*>(kp + (size_t)(16 + lm) * NTOK + coff);
    const s16x8 b0 = *reinterpret_cast<const s16x8*>(vp + (size_t)lm * NTOK + coff);
    const s16x8 b1 = *reinterpret_cast<const s16x8*>(vp + (size_t)(16 + lm) * NTOK + coff);
    acc[0][0] = __builtin_amdgcn_mfma_f32_16x16x32_bf16(a0, b0, acc[0][0], 0, 0, 0);
    acc[0][1] = __builtin_amdgcn_mfma_f32_16x16x32_bf16(a0, b1, acc[0][1], 0, 0, 0);
    acc[1][0] = __builtin_amdgcn_mfma_f32_16x16x32_bf16(a1, b0, acc[1][0], 0, 0, 0);
    acc[1][1] = __builtin_amdgcn_mfma_f32_16x16x32_bf16(a1, b1, acc[1][1], 0, 0, 0);
  }
  float* op = ctx_part + ((size_t)bh * 8 + seg) * 1024;
#pragma unroll
  for (int et = 0; et < 2; ++et)
#pragma unroll
    for (int dt = 0; dt < 2; ++dt)
#pragma unroll
      for (int r = 0; r < 4; ++r)
        op[(et * 16 + lk * 4 + r) * 32 + dt * 16 + lm] = acc[et][dt][r];
}

// ---------------------------------------------------------------------------
// K5: W2'[b][o][c'] = (sum_d w_out[o][h*32+d] * ctx[b][h][e][d]) * f[c'],
// f[c'] = SCALE / sum_n E[c'][n]. -> bf16. ctx sums 8 segment partials.
// ---------------------------------------------------------------------------
__global__ __launch_bounds__(256) void k_w2(const float* __restrict__ ctx_part,
                                            const float* __restrict__ spart,
                                            const float* __restrict__ w_out,
                                            ushort* __restrict__ W2b) {
  const int b = blockIdx.x;
  const int t = threadIdx.x;
  __shared__ float ctx[4096];
  __shared__ float fbuf[128];
#pragma unroll
  for (int i = 0; i < 16; ++i) {
    const int idx = t + 256 * i;
    const int h = idx >> 10, ed = idx & 1023;
    const float* cp = ctx_part + ((size_t)((b * 4 + h) * 8)) * 1024 + ed;
    float a = 0.f;
#pragma unroll
    for (int j = 0; j < 8; ++j) a += cp[j * 1024];
    ctx[idx] = a;
  }
  if (t < 128) {
    float s = 0.f;
    for (int p = 0; p < 64; ++p) s += spart[((size_t)b * 64 + p) * 128 + t];
    fbuf[t] = SCALE / s;
  }
  __syncthreads();
  const float* wrow = w_out + (size_t)t * 128;
  ushort* wout_row = W2b + ((size_t)b * 256 + t) * 128;
  float wv[32];
  for (int h = 0; h < 4; ++h) {
#pragma unroll
    for (int d = 0; d < 32; ++d) wv[d] = wrow[h * 32 + d];
#pragma unroll 4
    for (int e = 0; e < 32; ++e) {
      float a = 0.f;
#pragma unroll
      for (int d = 0; d < 32; ++d) a += wv[d] * ctx[h * 1024 + e * 32 + d];
      wout_row[h * 32 + e] = bf_rne(a * fbuf[h * 32 + e]);
    }
  }
}

// ---------------------------------------------------------------------------
// K6: out[b][o][n] = sum_c W2'[b][o][c] * E[b][c][n] + b_out[o], bf16 MFMA.
// BK=64, 2 iters. A via gl_lds (swizzled source), B gather staged.
// grid (32, 2, 32).  (at memory roofline: 134 MB fp32 output write)
// ---------------------------------------------------------------------------
__global__ __launch_bounds__(256) void k_out_mfma(const ushort* __restrict__ Ecn,
                                                  const ushort* __restrict__ W2b,
                                                  const float* __restrict__ b_out,
                                                  float* __restrict__ out) {
  const int n0 = blockIdx.x * 128;
  const int o0 = blockIdx.y * 128;
  const int b  = blockIdx.z;
  const ushort* A  = W2b + (size_t)b * 256 * 128;
  const ushort* Bq = Ecn + (size_t)b * 128 * NTOK;

  __shared__ ushort As[8192];
  __shared__ ushort Bt[8192];

  const int t = threadIdx.x;
  const int lane = t & 63;
  const int wv = t >> 6;
  const int wr = wv >> 1, wc = wv & 1;
  const int lm = lane & 15;
  const int lk = lane >> 4;

  int aoff[4][2], boff[4][2];
#pragma unroll
  for (int mf = 0; mf < 4; ++mf) {
    const int ar = wr * 64 + mf * 16 + lm;
#pragma unroll
    for (int ks = 0; ks < 2; ++ks)
      aoff[mf][ks] = ar * 64 + 8 * ((ks * 4 + lk) ^ (ar & 7));
  }
#pragma unroll
  for (int nf = 0; nf < 4; ++nf) {
    const int br = wc * 64 + nf * 16 + lm;
#pragma unroll
    for (int ks = 0; ks < 2; ++ks)
      boff[nf][ks] = br * 64 + 8 * ((ks * 4 + lk) ^ (br & 7));
  }
  size_t gaA[4];
  int lb[4];
#pragma unroll
  for (int i = 0; i < 4; ++i) {
    const int s_total = t + 256 * i;
    const int r = s_total >> 3;
    const int q = (s_total & 7) ^ (r & 7);
    gaA[i] = (size_t)(o0 + r) * 128 + q * 8;
    lb[i] = wv * 512 + i * 2048;
  }
  int bst[8], bn[8], bcg[8];
#pragma unroll
  for (int i = 0; i < 8; ++i) {
    const int u = t + 256 * i;
    bn[i] = u & 127;
    bcg[i] = u >> 7;
    bst[i] = bn[i] * 64 + 8 * ((bcg[i] >> 1) ^ (bn[i] & 7)) + (bcg[i] & 1) * 4;
  }

  f32x4 acc[4][4];
#pragma unroll
  for (int i = 0; i < 4; ++i)
#pragma unroll
    for (int j = 0; j < 4; ++j) acc[i][j] = (f32x4){0.f, 0.f, 0.f, 0.f};

  for (int it = 0; it < 2; ++it) {
    const size_t c0 = (size_t)it * 64;
    __syncthreads();
#pragma unroll
    for (int i = 0; i < 4; ++i)
      gl_lds16(A + gaA[i] + c0, As + lb[i]);
#pragma unroll
    for (int i = 0; i < 8; ++i) {
      const ushort* gp = Bq + (c0 + bcg[i] * 4) * NTOK + n0 + bn[i];
      ushort4 hvec;
      hvec.x = gp[0];
      hvec.y = gp[NTOK];
      hvec.z = gp[2 * NTOK];
      hvec.w = gp[3 * NTOK];
      *reinterpret_cast<ushort4*>(Bt + bst[i]) = hvec;
    }
    __syncthreads();
#pragma unroll
    for (int ks = 0; ks < 2; ++ks) {
      s16x8 af[4], bf[4];
#pragma unroll
      for (int mf = 0; mf < 4; ++mf)
        af[mf] = *reinterpret_cast<const s16x8*>(As + aoff[mf][ks]);
#pragma unroll
      for (int nf = 0; nf < 4; ++nf)
        bf[nf] = *reinterpret_cast<const s16x8*>(Bt + boff[nf][ks]);
#pragma unroll
      for (int mf = 0; mf < 4; ++mf)
#pragma unroll
        for (int nf = 0; nf < 4; ++nf)
          acc[mf][nf] = __builtin_amdgcn_mfma_f32_16x16x32_bf16(af[mf], bf[nf], acc[mf][nf], 0, 0, 0);
    }
  }

  float* C = out + ((size_t)b * 256 + o0) * NTOK + n0;
#pragma unroll
  for (int mf = 0; mf < 4; ++mf) {
    const int row0 = wr * 64 + mf * 16 + lk * 4;
#pragma unroll
    for (int nf = 0; nf < 4; ++nf) {
      const int col = wc * 64 + nf * 16 + lm;
#pragma unroll
      for (int r = 0; r < 4; ++r) {
        const float bias = b_out[o0 + row0 + r];
        C[(size_t)(row0 + r) * NTOK + col] = acc[mf][nf][r] + bias;
      }
    }
  }
}

extern "C" void kernel_launch(void* const* d_in, const int* in_sizes, int n_in,
                              void* d_out, int out_size, void* d_ws, size_t ws_size,
                              hipStream_t stream) {
  const float* x     = (const float*)d_in[0];
  const float* w_qkv = (const float*)d_in[1];
  const float* w_out = (const float*)d_in[2];
  const float* b_out = (const float*)d_in[3];
  float* out = (float*)d_out;

  ushort* kb  = (ushort*)d_ws;                          // 16777216 us (33.5MB)
  ushort* vb  = kb + (size_t)16777216;                  // 33.5MB
  ushort* Ecn = vb + (size_t)16777216;                  // 33.5MB
  float*  ctx_part = (float*)(Ecn + (size_t)16777216);  // 1048576 f32 (4MB)
  float*  spart    = ctx_part + 1048576;                // 262144 f32 (1MB)
  ushort* wb  = (ushort*)(spart + 262144);              // 98304 us
  ushort* W2b = wb + 98304;                             // 1048576 us (2MB)

  k_cvt_w<<<96, 256, 0, stream>>>(w_qkv, wb);
  k_qkv_mfma<<<dim3(32, 3, 32), 256, 0, stream>>>(x, wb, Ecn, kb, vb, spart);
  k_context_mfma<<<256, 256, 0, stream>>>(kb, vb, ctx_part);
  k_w2<<<32, 256, 0, stream>>>(ctx_part, spart, w_out, W2b);
  k_out_mfma<<<dim3(32, 2, 32), 256, 0, stream>>>(Ecn, W2b, b_out, out);
}

// Round 20
// 159.003 us; speedup vs baseline: 1.0856x; 1.0088x over previous
//
#include <hip/hip_runtime.h>
#include <hip/hip_bf16.h>

#define NTOK 4096
#define SCALE 0.17677669529663687f  /* 32^-0.5 */

// 16B-chunk XOR swizzle within a 64B (32-ushort) LDS row (K6 tiles).
#define SWZ(r) ((((r) >> 1) ^ ((r) >> 3)) & 3)

using f32x4 = __attribute__((ext_vector_type(4))) float;
using s16x8 = __attribute__((ext_vector_type(8))) short;
using v4i   = __attribute__((ext_vector_type(4))) int;

__device__ __forceinline__ ushort bf_rne(float f) {
  unsigned int u = __builtin_bit_cast(unsigned int, f);
  u += 0x7FFFu + ((u >> 16) & 1u);
  return (ushort)(u >> 16);
}
__device__ __forceinline__ unsigned int pk2(float a, float b) {
  __hip_bfloat162 h = __float22bfloat162_rn(make_float2(a, b));
  unsigned int u;
  __builtin_memcpy(&u, &h, 4);
  return u;
}
__device__ __forceinline__ void gl_lds16(const ushort* g, ushort* l) {
  __builtin_amdgcn_global_load_lds(
      (const __attribute__((address_space(1))) unsigned int*)g,
      (__attribute__((address_space(3))) unsigned int*)l, 16, 0, 0);
}
__device__ __forceinline__ v4i make_srsrc(const void* p) {
  union {
    struct { const void* p; unsigned nr; unsigned fl; } s;
    v4i v;
  } u;
  u.s.p = p;
  u.s.nr = 0xFFFFFFFFu;
  u.s.fl = 0x00020000u;
  return u.v;
}
#if __has_builtin(__builtin_amdgcn_raw_buffer_load_f32)
#define HAVE_RAW_BL 1
#else
#define HAVE_RAW_BL 0
#endif

// ---------------------------------------------------------------------------
// K0: w_qkv (384x256 f32) -> bf16 RNE. grid 96 x 256.
// ---------------------------------------------------------------------------
__global__ __launch_bounds__(256) void k_cvt_w(const float* __restrict__ w,
                                               ushort* __restrict__ wb) {
  const int i = blockIdx.x * 256 + threadIdx.x;
  const float4 v = reinterpret_cast<const float4*>(w)[i];
  ushort4 h;
  h.x = bf_rne(v.x); h.y = bf_rne(v.y); h.z = bf_rne(v.z); h.w = bf_rne(v.w);
  reinterpret_cast<ushort4*>(wb)[i] = h;
}

// ---------------------------------------------------------------------------
// K1 (A-persistent, BK=64, 8 WAVES): qkv = w @ x from x f32 [c][n].
// 128x128 tile, 512 threads (8 waves, each a 32x64 sub-tile: acc[2][4]) ->
// 4 waves/SIMD at the same 80KB/2-block LDS footprint (doubles latency
// hiding vs round 19's 2 waves/SIMD). A (64KB bf16) staged once; B tile
// 64c x 128n reg-staged depth-1; 4 iters x 16 MFMA/wave; counted waits +
// raw barriers; setprio around MFMA. Epilogue: y==0 -> E=exp(q) [c][n] +
// row sums; y==1 -> softmax-d -> kb (each wave's 32 rows = one head);
// y==2 -> vb. grid (32 n, 3 o, 32 b) x 512.
// ---------------------------------------------------------------------------
__global__ __launch_bounds__(512) void k_qkv_mfma(const float* __restrict__ x,
                                                  const ushort* __restrict__ wb,
                                                  ushort* __restrict__ Ecn,
                                                  ushort* __restrict__ kb,
                                                  ushort* __restrict__ vb,
                                                  float* __restrict__ spart) {
  const int n0 = blockIdx.x * 128;
  const int o0 = blockIdx.y * 128;
  const int b  = blockIdx.z;
  const float* xb = x + (size_t)b * 256 * NTOK;

  __shared__ ushort As[128 * 256];  // 64KB: [o-row][c], 32 chunks/row, ^(row&31)
  __shared__ ushort Bs[128 * 64];   // 16KB: [n][64c], 8 chunks/row, ^(n&7)

  const int t = threadIdx.x;
  const int lane = t & 63;
  const int wv = t >> 6;            // 0..7
  const int wr = wv & 3;            // row group (32 rows)
  const int wc = wv >> 2;           // col half (64 cols)
  const int lm = lane & 15;
  const int lk = lane >> 4;

  // fragment rows
  int arow[2], brow[4];
#pragma unroll
  for (int mf = 0; mf < 2; ++mf) arow[mf] = wr * 32 + mf * 16 + lm;
#pragma unroll
  for (int nf = 0; nf < 4; ++nf) brow[nf] = wc * 64 + nf * 16 + lm;

  // B staging: unit u = t + 512*i (i<2) -> (n = u&127, c-oct = u>>7, 0..7)
  int sst[2], sn[2], sco[2];
#pragma unroll
  for (int i = 0; i < 2; ++i) {
    const int u = t + 512 * i;
    sn[i] = u & 127;
    sco[i] = u >> 7;
    sst[i] = sn[i] * 64 + 8 * (sco[i] ^ (sn[i] & 7));
  }
  const float* xbn = xb + n0;
  const v4i rx = make_srsrc(xbn);
  int voff[2];
#pragma unroll
  for (int i = 0; i < 2; ++i) voff[i] = (sco[i] * 8 * NTOK + sn[i]) * 4;

#if HAVE_RAW_BL
#define BLOAD(i, j, itc) __builtin_amdgcn_raw_buffer_load_f32(rx, voff[i], (itc) * 1048576 + (j) * 16384, 0)
#else
#define BLOAD(i, j, itc) xbn[(size_t)((itc) * 64 + sco[i] * 8 + (j)) * NTOK + sn[i]]
#endif

  // ---- prologue: stage ALL of A once (4096 chunks / 512 thr = 8 ea) ----
#pragma unroll
  for (int i = 0; i < 8; ++i) {
    const int s = i * 512 + t;
    const int row = s >> 5;
    const int q = (s & 31) ^ (row & 31);
    gl_lds16(wb + (size_t)(o0 + row) * 256 + q * 8,
             As + (size_t)(i * 512 + wv * 64) * 8);
  }
  float pre[16];
#pragma unroll
  for (int i = 0; i < 2; ++i)
#pragma unroll
    for (int j = 0; j < 8; ++j) pre[i * 8 + j] = BLOAD(i, j, 0);
  __syncthreads();  // drains A gl_lds + P(0); one-time cost

  f32x4 acc[2][4];
#pragma unroll
  for (int i = 0; i < 2; ++i)
#pragma unroll
    for (int j = 0; j < 4; ++j) acc[i][j] = (f32x4){0.f, 0.f, 0.f, 0.f};

#pragma unroll
  for (int it = 0; it < 4; ++it) {
    if (it > 0) {
      __builtin_amdgcn_sched_barrier(0);
      asm volatile("s_waitcnt vmcnt(0)" ::: "memory");
      __builtin_amdgcn_sched_barrier(0);
    }
    // ---- stage B from pre regs (2x b128 writes) ----
#pragma unroll
    for (int i = 0; i < 2; ++i) {
      union { s16x8 v; unsigned int u[4]; } pk;
      pk.u[0] = pk2(pre[i * 8 + 0], pre[i * 8 + 1]);
      pk.u[1] = pk2(pre[i * 8 + 2], pre[i * 8 + 3]);
      pk.u[2] = pk2(pre[i * 8 + 4], pre[i * 8 + 5]);
      pk.u[3] = pk2(pre[i * 8 + 6], pre[i * 8 + 7]);
      *reinterpret_cast<s16x8*>(Bs + sst[i]) = pk.v;
    }
    // ---- issue P(it+1): full iteration of latency cover ----
    if (it < 3) {
#pragma unroll
      for (int i = 0; i < 2; ++i)
#pragma unroll
        for (int j = 0; j < 8; ++j) pre[i * 8 + j] = BLOAD(i, j, it + 1);
    }
    // ---- Bs visible to all waves (prefetch stays in flight) ----
    __builtin_amdgcn_sched_barrier(0);
    asm volatile("s_waitcnt lgkmcnt(0)" ::: "memory");
    __builtin_amdgcn_sched_barrier(0);
    __builtin_amdgcn_s_barrier();
    __builtin_amdgcn_sched_barrier(0);
    // ---- MFMA phase: 2 k-slices x 8 MFMA/wave ----
    __builtin_amdgcn_s_setprio(1);
#pragma unroll
    for (int ks = 0; ks < 2; ++ks) {
      s16x8 af[2], bf[4];
#pragma unroll
      for (int mf = 0; mf < 2; ++mf) {
        const int sc = (it * 8 + ks * 4 + lk) ^ (arow[mf] & 31);
        af[mf] = *reinterpret_cast<const s16x8*>(As + arow[mf] * 256 + 8 * sc);
      }
#pragma unroll
      for (int nf = 0; nf < 4; ++nf) {
        const int bc = (ks * 4 + lk) ^ (brow[nf] & 7);
        bf[nf] = *reinterpret_cast<const s16x8*>(Bs + brow[nf] * 64 + 8 * bc);
      }
#pragma unroll
      for (int mf = 0; mf < 2; ++mf)
#pragma unroll
        for (int nf = 0; nf < 4; ++nf)
          acc[mf][nf] = __builtin_amdgcn_mfma_f32_16x16x32_bf16(af[mf], bf[nf], acc[mf][nf], 0, 0, 0);
    }
    __builtin_amdgcn_s_setprio(0);
    // ---- protect Bs before next iter's overwrite ----
    __builtin_amdgcn_sched_barrier(0);
    __builtin_amdgcn_s_barrier();
    __builtin_amdgcn_sched_barrier(0);
  }
#undef BLOAD

  if (blockIdx.y == 0) {
    // q path: E = exp(q), [c][n] layout + row-sum partials
    ushort* C = Ecn + (size_t)b * 128 * NTOK + n0;
    float* sp = spart + (((size_t)b * 32 + blockIdx.x) * 2 + wc) * 128;
#pragma unroll
    for (int mf = 0; mf < 2; ++mf) {
#pragma unroll
      for (int r = 0; r < 4; ++r) {
        const int ch = wr * 32 + mf * 16 + lk * 4 + r;
        float s = 0.f;
#pragma unroll
        for (int nf = 0; nf < 4; ++nf) {
          const float e = __expf(acc[mf][nf][r]);
          s += e;
          C[(size_t)ch * NTOK + wc * 64 + nf * 16 + lm] = bf_rne(e);
        }
        s += __shfl_xor(s, 1, 64);
        s += __shfl_xor(s, 2, 64);
        s += __shfl_xor(s, 4, 64);
        s += __shfl_xor(s, 8, 64);
        if (lm == 0) sp[ch] = s;
      }
    }
  } else if (blockIdx.y == 1) {
    // k path: softmax over d. Wave rows = one head (h = wr): 8 in-lane vals
    // (mf x r) x 4 lk lanes = 32 d's per column.
#pragma unroll
    for (int nf = 0; nf < 4; ++nf) {
      float m = -1e30f;
#pragma unroll
      for (int mf = 0; mf < 2; ++mf)
#pragma unroll
        for (int r = 0; r < 4; ++r)
          m = fmaxf(m, acc[mf][nf][r]);
      m = fmaxf(m, __shfl_xor(m, 16, 64));
      m = fmaxf(m, __shfl_xor(m, 32, 64));
      float s = 0.f;
#pragma unroll
      for (int mf = 0; mf < 2; ++mf)
#pragma unroll
        for (int r = 0; r < 4; ++r) {
          const float e = __expf(acc[mf][nf][r] - m);
          acc[mf][nf][r] = e;
          s += e;
        }
      s += __shfl_xor(s, 16, 64);
      s += __shfl_xor(s, 32, 64);
      const float inv = 1.0f / s;
#pragma unroll
      for (int mf = 0; mf < 2; ++mf)
#pragma unroll
        for (int r = 0; r < 4; ++r) acc[mf][nf][r] *= inv;
    }
    ushort* C = kb + (size_t)b * 128 * NTOK + n0;
#pragma unroll
    for (int mf = 0; mf < 2; ++mf) {
      const int row0 = wr * 32 + mf * 16 + lk * 4;
#pragma unroll
      for (int nf = 0; nf < 4; ++nf) {
        const int col = wc * 64 + nf * 16 + lm;
#pragma unroll
        for (int r = 0; r < 4; ++r)
          C[(size_t)(row0 + r) * NTOK + col] = bf_rne(acc[mf][nf][r]);
      }
    }
  } else {
    ushort* C = vb + (size_t)b * 128 * NTOK + n0;
#pragma unroll
    for (int mf = 0; mf < 2; ++mf) {
      const int row0 = wr * 32 + mf * 16 + lk * 4;
#pragma unroll
      for (int nf = 0; nf < 4; ++nf) {
        const int col = wc * 64 + nf * 16 + lm;
#pragma unroll
        for (int r = 0; r < 4; ++r)
          C[(size_t)(row0 + r) * NTOK + col] = bf_rne(acc[mf][nf][r]);
      }
    }
  }
}

// ---------------------------------------------------------------------------
// K2: context partials via bf16 MFMA. grid 256 = bh(128) x half(2);
// 4 waves x 512 tokens each -> 8 segments/bh (full CU coverage).
// ---------------------------------------------------------------------------
__global__ __launch_bounds__(256) void k_context_mfma(const ushort* __restrict__ kb,
                                                      const ushort* __restrict__ vb,
                                                      float* __restrict__ ctx_part) {
  const int bh = blockIdx.x >> 1;
  const int half = blockIdx.x & 1;
  const int w = threadIdx.x >> 6;
  const int seg = half * 4 + w;
  const int lane = threadIdx.x & 63;
  const int lm = lane & 15, lk = lane >> 4;
  const ushort* kp = kb + (size_t)bh * 32 * NTOK + (size_t)seg * 512;
  const ushort* vp = vb + (size_t)bh * 32 * NTOK + (size_t)seg * 512;
  f32x4 acc[2][2];
#pragma unroll
  for (int i = 0; i < 2; ++i)
#pragma unroll
    for (int j = 0; j < 2; ++j) acc[i][j] = (f32x4){0.f, 0.f, 0.f, 0.f};
#pragma unroll 4
  for (int ks = 0; ks < 16; ++ks) {
    const int coff = ks * 32 + lk * 8;
    const s16x8 a0 = *reinterpret_cast<const s16x8*>(kp + (size_t)lm * NTOK + coff);
    const s16x8 a1 = *reinterpret_cast<const s16x8*>(kp + (size_t)(16 + lm) * NTOK + coff);
    const s16x8 b0 = *reinterpret_cast<const s16x8*>(vp + (size_t)lm * NTOK + coff);
    const s16x8 b1 = *reinterpret_cast<const s16x8*>(vp + (size_t)(16 + lm) * NTOK + coff);
    acc[0][0] = __builtin_amdgcn_mfma_f32_16x16x32_bf16(a0, b0, acc[0][0], 0, 0, 0);
    acc[0][1] = __builtin_amdgcn_mfma_f32_16x16x32_bf16(a0, b1, acc[0][1], 0, 0, 0);
    acc[1][0] = __builtin_amdgcn_mfma_f32_16x16x32_bf16(a1, b0, acc[1][0], 0, 0, 0);
    acc[1][1] = __builtin_amdgcn_mfma_f32_16x16x32_bf16(a1, b1, acc[1][1], 0, 0, 0);
  }
  float* op = ctx_part + ((size_t)bh * 8 + seg) * 1024;
#pragma unroll
  for (int et = 0; et < 2; ++et)
#pragma unroll
    for (int dt = 0; dt < 2; ++dt)
#pragma unroll
      for (int r = 0; r < 4; ++r)
        op[(et * 16 + lk * 4 + r) * 32 + dt * 16 + lm] = acc[et][dt][r];
}

// ---------------------------------------------------------------------------
// K5: W2'[b][o][c'] = (sum_d w_out[o][h*32+d] * ctx[b][h][e][d]) * f[c'],
// f[c'] = SCALE / sum_n E[c'][n]. -> bf16. ctx sums 8 segment partials.
// ---------------------------------------------------------------------------
__global__ __launch_bounds__(256) void k_w2(const float* __restrict__ ctx_part,
                                            const float* __restrict__ spart,
                                            const float* __restrict__ w_out,
                                            ushort* __restrict__ W2b) {
  const int b = blockIdx.x;
  const int t = threadIdx.x;
  __shared__ float ctx[4096];
  __shared__ float fbuf[128];
#pragma unroll
  for (int i = 0; i < 16; ++i) {
    const int idx = t + 256 * i;
    const int h = idx >> 10, ed = idx & 1023;
    const float* cp = ctx_part + ((size_t)((b * 4 + h) * 8)) * 1024 + ed;
    float a = 0.f;
#pragma unroll
    for (int j = 0; j < 8; ++j) a += cp[j * 1024];
    ctx[idx] = a;
  }
  if (t < 128) {
    float s = 0.f;
    for (int p = 0; p < 64; ++p) s += spart[((size_t)b * 64 + p) * 128 + t];
    fbuf[t] = SCALE / s;
  }
  __syncthreads();
  const float* wrow = w_out + (size_t)t * 128;
  ushort* wout_row = W2b + ((size_t)b * 256 + t) * 128;
  float wv[32];
  for (int h = 0; h < 4; ++h) {
#pragma unroll
    for (int d = 0; d < 32; ++d) wv[d] = wrow[h * 32 + d];
#pragma unroll 4
    for (int e = 0; e < 32; ++e) {
      float a = 0.f;
#pragma unroll
      for (int d = 0; d < 32; ++d) a += wv[d] * ctx[h * 1024 + e * 32 + d];
      wout_row[h * 32 + e] = bf_rne(a * fbuf[h * 32 + e]);
    }
  }
}

// ---------------------------------------------------------------------------
// K6: out[b][o][n] = sum_c W2'[b][o][c] * E[b][c][n] + b_out[o], bf16 MFMA.
// BK=64, 2 iters. A via gl_lds (swizzled source), B gather staged.
// grid (32, 2, 32).  (at memory roofline: 134 MB fp32 output write)
// ---------------------------------------------------------------------------
__global__ __launch_bounds__(256) void k_out_mfma(const ushort* __restrict__ Ecn,
                                                  const ushort* __restrict__ W2b,
                                                  const float* __restrict__ b_out,
                                                  float* __restrict__ out) {
  const int n0 = blockIdx.x * 128;
  const int o0 = blockIdx.y * 128;
  const int b  = blockIdx.z;
  const ushort* A  = W2b + (size_t)b * 256 * 128;
  const ushort* Bq = Ecn + (size_t)b * 128 * NTOK;

  __shared__ ushort As[8192];
  __shared__ ushort Bt[8192];

  const int t = threadIdx.x;
  const int lane = t & 63;
  const int wv = t >> 6;
  const int wr = wv >> 1, wc = wv & 1;
  const int lm = lane & 15;
  const int lk = lane >> 4;

  int aoff[4][2], boff[4][2];
#pragma unroll
  for (int mf = 0; mf < 4; ++mf) {
    const int ar = wr * 64 + mf * 16 + lm;
#pragma unroll
    for (int ks = 0; ks < 2; ++ks)
      aoff[mf][ks] = ar * 64 + 8 * ((ks * 4 + lk) ^ (ar & 7));
  }
#pragma unroll
  for (int nf = 0; nf < 4; ++nf) {
    const int br = wc * 64 + nf * 16 + lm;
#pragma unroll
    for (int ks = 0; ks < 2; ++ks)
      boff[nf][ks] = br * 64 + 8 * ((ks * 4 + lk) ^ (br & 7));
  }
  size_t gaA[4];
  int lb[4];
#pragma unroll
  for (int i = 0; i < 4; ++i) {
    const int s_total = t + 256 * i;
    const int r = s_total >> 3;
    const int q = (s_total & 7) ^ (r & 7);
    gaA[i] = (size_t)(o0 + r) * 128 + q * 8;
    lb[i] = wv * 512 + i * 2048;
  }
  int bst[8], bn[8], bcg[8];
#pragma unroll
  for (int i = 0; i < 8; ++i) {
    const int u = t + 256 * i;
    bn[i] = u & 127;
    bcg[i] = u >> 7;
    bst[i] = bn[i] * 64 + 8 * ((bcg[i] >> 1) ^ (bn[i] & 7)) + (bcg[i] & 1) * 4;
  }

  f32x4 acc[4][4];
#pragma unroll
  for (int i = 0; i < 4; ++i)
#pragma unroll
    for (int j = 0; j < 4; ++j) acc[i][j] = (f32x4){0.f, 0.f, 0.f, 0.f};

  for (int it = 0; it < 2; ++it) {
    const size_t c0 = (size_t)it * 64;
    __syncthreads();
#pragma unroll
    for (int i = 0; i < 4; ++i)
      gl_lds16(A + gaA[i] + c0, As + lb[i]);
#pragma unroll
    for (int i = 0; i < 8; ++i) {
      const ushort* gp = Bq + (c0 + bcg[i] * 4) * NTOK + n0 + bn[i];
      ushort4 hvec;
      hvec.x = gp[0];
      hvec.y = gp[NTOK];
      hvec.z = gp[2 * NTOK];
      hvec.w = gp[3 * NTOK];
      *reinterpret_cast<ushort4*>(Bt + bst[i]) = hvec;
    }
    __syncthreads();
#pragma unroll
    for (int ks = 0; ks < 2; ++ks) {
      s16x8 af[4], bf[4];
#pragma unroll
      for (int mf = 0; mf < 4; ++mf)
        af[mf] = *reinterpret_cast<const s16x8*>(As + aoff[mf][ks]);
#pragma unroll
      for (int nf = 0; nf < 4; ++nf)
        bf[nf] = *reinterpret_cast<const s16x8*>(Bt + boff[nf][ks]);
#pragma unroll
      for (int mf = 0; mf < 4; ++mf)
#pragma unroll
        for (int nf = 0; nf < 4; ++nf)
          acc[mf][nf] = __builtin_amdgcn_mfma_f32_16x16x32_bf16(af[mf], bf[nf], acc[mf][nf], 0, 0, 0);
    }
  }

  float* C = out + ((size_t)b * 256 + o0) * NTOK + n0;
#pragma unroll
  for (int mf = 0; mf < 4; ++mf) {
    const int row0 = wr * 64 + mf * 16 + lk * 4;
#pragma unroll
    for (int nf = 0; nf < 4; ++nf) {
      const int col = wc * 64 + nf * 16 + lm;
#pragma unroll
      for (int r = 0; r < 4; ++r) {
        const float bias = b_out[o0 + row0 + r];
        C[(size_t)(row0 + r) * NTOK + col] = acc[mf][nf][r] + bias;
      }
    }
  }
}

extern "C" void kernel_launch(void* const* d_in, const int* in_sizes, int n_in,
                              void* d_out, int out_size, void* d_ws, size_t ws_size,
                              hipStream_t stream) {
  const float* x     = (const float*)d_in[0];
  const float* w_qkv = (const float*)d_in[1];
  const float* w_out = (const float*)d_in[2];
  const float* b_out = (const float*)d_in[3];
  float* out = (float*)d_out;

  ushort* kb  = (ushort*)d_ws;                          // 16777216 us (33.5MB)
  ushort* vb  = kb + (size_t)16777216;                  // 33.5MB
  ushort* Ecn = vb + (size_t)16777216;                  // 33.5MB
  float*  ctx_part = (float*)(Ecn + (size_t)16777216);  // 1048576 f32 (4MB)
  float*  spart    = ctx_part + 1048576;                // 262144 f32 (1MB)
  ushort* wb  = (ushort*)(spart + 262144);              // 98304 us
  ushort* W2b = wb + 98304;                             // 1048576 us (2MB)

  k_cvt_w<<<96, 256, 0, stream>>>(w_qkv, wb);
  k_qkv_mfma<<<dim3(32, 3, 32), 512, 0, stream>>>(x, wb, Ecn, kb, vb, spart);
  k_context_mfma<<<256, 256, 0, stream>>>(kb, vb, ctx_part);
  k_w2<<<32, 256, 0, stream>>>(ctx_part, spart, w_out, W2b);
  k_out_mfma<<<dim3(32, 2, 32), 256, 0, stream>>>(Ecn, W2b, b_out, out);
}

// Round 21
// 158.006 us; speedup vs baseline: 1.0925x; 1.0063x over previous
//
#include <hip/hip_runtime.h>
#include <hip/hip_bf16.h>

#define NTOK 4096
#define SCALE 0.17677669529663687f  /* 32^-0.5 */

// 16B-chunk XOR swizzle within a 64B (32-ushort) LDS row (K6 tiles).
#define SWZ(r) ((((r) >> 1) ^ ((r) >> 3)) & 3)

using f32x4 = __attribute__((ext_vector_type(4))) float;
using s16x8 = __attribute__((ext_vector_type(8))) short;
using v4i   = __attribute__((ext_vector_type(4))) int;

__device__ __forceinline__ ushort bf_rne(float f) {
  unsigned int u = __builtin_bit_cast(unsigned int, f);
  u += 0x7FFFu + ((u >> 16) & 1u);
  return (ushort)(u >> 16);
}
__device__ __forceinline__ unsigned int pk2(float a, float b) {
  __hip_bfloat162 h = __float22bfloat162_rn(make_float2(a, b));
  unsigned int u;
  __builtin_memcpy(&u, &h, 4);
  return u;
}
__device__ __forceinline__ void gl_lds16(const ushort* g, ushort* l) {
  __builtin_amdgcn_global_load_lds(
      (const __attribute__((address_space(1))) unsigned int*)g,
      (__attribute__((address_space(3))) unsigned int*)l, 16, 0, 0);
}
__device__ __forceinline__ v4i make_srsrc(const void* p) {
  union {
    struct { const void* p; unsigned nr; unsigned fl; } s;
    v4i v;
  } u;
  u.s.p = p;
  u.s.nr = 0xFFFFFFFFu;
  u.s.fl = 0x00020000u;
  return u.v;
}
#if __has_builtin(__builtin_amdgcn_raw_buffer_load_f32)
#define HAVE_RAW_BL 1
#else
#define HAVE_RAW_BL 0
#endif

// ---------------------------------------------------------------------------
// K0: w_qkv (384x256 f32) -> bf16 RNE. grid 96 x 256.
// ---------------------------------------------------------------------------
__global__ __launch_bounds__(256) void k_cvt_w(const float* __restrict__ w,
                                               ushort* __restrict__ wb) {
  const int i = blockIdx.x * 256 + threadIdx.x;
  const float4 v = reinterpret_cast<const float4*>(w)[i];
  ushort4 h;
  h.x = bf_rne(v.x); h.y = bf_rne(v.y); h.z = bf_rne(v.z); h.w = bf_rne(v.w);
  reinterpret_cast<ushort4*>(wb)[i] = h;
}

// ---------------------------------------------------------------------------
// K1 (A-persistent, BK=64, 8 waves, DEPTH-2 prefetch + counted vmcnt):
// qkv = w @ x from x f32 [c][n]. 128x128 tile, 512 threads; A (64KB bf16)
// staged once; B tile 64c x 128n reg-staged with depth-2 pipeline (32
// loads/wave in flight, vmcnt(16) waits -- each batch gets ~2 iterations
// of latency cover). 4 iters x 16 MFMA/wave; raw barriers; setprio.
// Epilogue: y==0 -> E=exp(q) [c][n] + row sums; y==1 -> softmax-d -> kb;
// y==2 -> vb. grid (32 n, 3 o, 32 b) x 512.
// ---------------------------------------------------------------------------
__global__ __launch_bounds__(512) void k_qkv_mfma(const float* __restrict__ x,
                                                  const ushort* __restrict__ wb,
                                                  ushort* __restrict__ Ecn,
                                                  ushort* __restrict__ kb,
                                                  ushort* __restrict__ vb,
                                                  float* __restrict__ spart) {
  const int n0 = blockIdx.x * 128;
  const int o0 = blockIdx.y * 128;
  const int b  = blockIdx.z;
  const float* xb = x + (size_t)b * 256 * NTOK;

  __shared__ ushort As[128 * 256];  // 64KB: [o-row][c], 32 chunks/row, ^(row&31)
  __shared__ ushort Bs[128 * 64];   // 16KB: [n][64c], 8 chunks/row, ^(n&7)

  const int t = threadIdx.x;
  const int lane = t & 63;
  const int wv = t >> 6;            // 0..7
  const int wr = wv & 3;            // row group (32 rows)
  const int wc = wv >> 2;           // col half (64 cols)
  const int lm = lane & 15;
  const int lk = lane >> 4;

  int arow[2], brow[4];
#pragma unroll
  for (int mf = 0; mf < 2; ++mf) arow[mf] = wr * 32 + mf * 16 + lm;
#pragma unroll
  for (int nf = 0; nf < 4; ++nf) brow[nf] = wc * 64 + nf * 16 + lm;

  // B staging: unit u = t + 512*i (i<2) -> (n = u&127, c-oct = u>>7, 0..7)
  int sst[2], sn[2], sco[2];
#pragma unroll
  for (int i = 0; i < 2; ++i) {
    const int u = t + 512 * i;
    sn[i] = u & 127;
    sco[i] = u >> 7;
    sst[i] = sn[i] * 64 + 8 * (sco[i] ^ (sn[i] & 7));
  }
  const float* xbn = xb + n0;
  const v4i rx = make_srsrc(xbn);
  int voff[2];
#pragma unroll
  for (int i = 0; i < 2; ++i) voff[i] = (sco[i] * 8 * NTOK + sn[i]) * 4;

#if HAVE_RAW_BL
#define BLOAD(i, j, itc) __builtin_amdgcn_raw_buffer_load_f32(rx, voff[i], (itc) * 1048576 + (j) * 16384, 0)
#else
#define BLOAD(i, j, itc) xbn[(size_t)((itc) * 64 + sco[i] * 8 + (j)) * NTOK + sn[i]]
#endif

  // ---- prologue: stage ALL of A once; P(0); drain; then issue P(1) ----
#pragma unroll
  for (int i = 0; i < 8; ++i) {
    const int s = i * 512 + t;
    const int row = s >> 5;
    const int q = (s & 31) ^ (row & 31);
    gl_lds16(wb + (size_t)(o0 + row) * 256 + q * 8,
             As + (size_t)(i * 512 + wv * 64) * 8);
  }
  float preA[16], preB[16];
#pragma unroll
  for (int i = 0; i < 2; ++i)
#pragma unroll
    for (int j = 0; j < 8; ++j) preA[i * 8 + j] = BLOAD(i, j, 0);
  __syncthreads();  // drains A gl_lds + P(0); one-time cost
#pragma unroll
  for (int i = 0; i < 2; ++i)
#pragma unroll
    for (int j = 0; j < 8; ++j) preB[i * 8 + j] = BLOAD(i, j, 1);

  f32x4 acc[2][4];
#pragma unroll
  for (int i = 0; i < 2; ++i)
#pragma unroll
    for (int j = 0; j < 4; ++j) acc[i][j] = (f32x4){0.f, 0.f, 0.f, 0.f};

#pragma unroll
  for (int it = 0; it < 4; ++it) {
    // ---- land P(it): counted wait keeps P(it+1) in flight ----
    if (it >= 1) {
      __builtin_amdgcn_sched_barrier(0);
      if (it < 3) {
        asm volatile("s_waitcnt vmcnt(16)" ::: "memory");
      } else {
        asm volatile("s_waitcnt vmcnt(0)" ::: "memory");
      }
      __builtin_amdgcn_sched_barrier(0);
    }
    // ---- stage B from P(it) regs (static it -> static buffer choice) ----
    float* cur = (it & 1) ? preB : preA;
#pragma unroll
    for (int i = 0; i < 2; ++i) {
      union { s16x8 v; unsigned int u[4]; } pk;
      pk.u[0] = pk2(cur[i * 8 + 0], cur[i * 8 + 1]);
      pk.u[1] = pk2(cur[i * 8 + 2], cur[i * 8 + 3]);
      pk.u[2] = pk2(cur[i * 8 + 4], cur[i * 8 + 5]);
      pk.u[3] = pk2(cur[i * 8 + 6], cur[i * 8 + 7]);
      *reinterpret_cast<s16x8*>(Bs + sst[i]) = pk.v;
    }
    // ---- issue P(it+2) into the just-freed buffer ----
    if (it + 2 < 4) {
#pragma unroll
      for (int i = 0; i < 2; ++i)
#pragma unroll
        for (int j = 0; j < 8; ++j) cur[i * 8 + j] = BLOAD(i, j, it + 2);
    }
    // ---- Bs visible to all waves (prefetches stay in flight) ----
    __builtin_amdgcn_sched_barrier(0);
    asm volatile("s_waitcnt lgkmcnt(0)" ::: "memory");
    __builtin_amdgcn_sched_barrier(0);
    __builtin_amdgcn_s_barrier();
    __builtin_amdgcn_sched_barrier(0);
    // ---- MFMA phase: 2 k-slices x 8 MFMA/wave ----
    __builtin_amdgcn_s_setprio(1);
#pragma unroll
    for (int ks = 0; ks < 2; ++ks) {
      s16x8 af[2], bf[4];
#pragma unroll
      for (int mf = 0; mf < 2; ++mf) {
        const int sc = (it * 8 + ks * 4 + lk) ^ (arow[mf] & 31);
        af[mf] = *reinterpret_cast<const s16x8*>(As + arow[mf] * 256 + 8 * sc);
      }
#pragma unroll
      for (int nf = 0; nf < 4; ++nf) {
        const int bc = (ks * 4 + lk) ^ (brow[nf] & 7);
        bf[nf] = *reinterpret_cast<const s16x8*>(Bs + brow[nf] * 64 + 8 * bc);
      }
#pragma unroll
      for (int mf = 0; mf < 2; ++mf)
#pragma unroll
        for (int nf = 0; nf < 4; ++nf)
          acc[mf][nf] = __builtin_amdgcn_mfma_f32_16x16x32_bf16(af[mf], bf[nf], acc[mf][nf], 0, 0, 0);
    }
    __builtin_amdgcn_s_setprio(0);
    // ---- protect Bs before next iter's overwrite ----
    __builtin_amdgcn_sched_barrier(0);
    __builtin_amdgcn_s_barrier();
    __builtin_amdgcn_sched_barrier(0);
  }
#undef BLOAD

  if (blockIdx.y == 0) {
    // q path: E = exp(q), [c][n] layout + row-sum partials
    ushort* C = Ecn + (size_t)b * 128 * NTOK + n0;
    float* sp = spart + (((size_t)b * 32 + blockIdx.x) * 2 + wc) * 128;
#pragma unroll
    for (int mf = 0; mf < 2; ++mf) {
#pragma unroll
      for (int r = 0; r < 4; ++r) {
        const int ch = wr * 32 + mf * 16 + lk * 4 + r;
        float s = 0.f;
#pragma unroll
        for (int nf = 0; nf < 4; ++nf) {
          const float e = __expf(acc[mf][nf][r]);
          s += e;
          C[(size_t)ch * NTOK + wc * 64 + nf * 16 + lm] = bf_rne(e);
        }
        s += __shfl_xor(s, 1, 64);
        s += __shfl_xor(s, 2, 64);
        s += __shfl_xor(s, 4, 64);
        s += __shfl_xor(s, 8, 64);
        if (lm == 0) sp[ch] = s;
      }
    }
  } else if (blockIdx.y == 1) {
    // k path: softmax over d (wave rows = one head, h = wr)
#pragma unroll
    for (int nf = 0; nf < 4; ++nf) {
      float m = -1e30f;
#pragma unroll
      for (int mf = 0; mf < 2; ++mf)
#pragma unroll
        for (int r = 0; r < 4; ++r)
          m = fmaxf(m, acc[mf][nf][r]);
      m = fmaxf(m, __shfl_xor(m, 16, 64));
      m = fmaxf(m, __shfl_xor(m, 32, 64));
      float s = 0.f;
#pragma unroll
      for (int mf = 0; mf < 2; ++mf)
#pragma unroll
        for (int r = 0; r < 4; ++r) {
          const float e = __expf(acc[mf][nf][r] - m);
          acc[mf][nf][r] = e;
          s += e;
        }
      s += __shfl_xor(s, 16, 64);
      s += __shfl_xor(s, 32, 64);
      const float inv = 1.0f / s;
#pragma unroll
      for (int mf = 0; mf < 2; ++mf)
#pragma unroll
        for (int r = 0; r < 4; ++r) acc[mf][nf][r] *= inv;
    }
    ushort* C = kb + (size_t)b * 128 * NTOK + n0;
#pragma unroll
    for (int mf = 0; mf < 2; ++mf) {
      const int row0 = wr * 32 + mf * 16 + lk * 4;
#pragma unroll
      for (int nf = 0; nf < 4; ++nf) {
        const int col = wc * 64 + nf * 16 + lm;
#pragma unroll
        for (int r = 0; r < 4; ++r)
          C[(size_t)(row0 + r) * NTOK + col] = bf_rne(acc[mf][nf][r]);
      }
    }
  } else {
    ushort* C = vb + (size_t)b * 128 * NTOK + n0;
#pragma unroll
    for (int mf = 0; mf < 2; ++mf) {
      const int row0 = wr * 32 + mf * 16 + lk * 4;
#pragma unroll
      for (int nf = 0; nf < 4; ++nf) {
        const int col = wc * 64 + nf * 16 + lm;
#pragma unroll
        for (int r = 0; r < 4; ++r)
          C[(size_t)(row0 + r) * NTOK + col] = bf_rne(acc[mf][nf][r]);
      }
    }
  }
}

// ---------------------------------------------------------------------------
// K2: context partials via bf16 MFMA. grid 256 = bh(128) x half(2);
// 4 waves x 512 tokens each -> 8 segments/bh (full CU coverage).
// ---------------------------------------------------------------------------
__global__ __launch_bounds__(256) void k_context_mfma(const ushort* __restrict__ kb,
                                                      const ushort* __restrict__ vb,
                                                      float* __restrict__ ctx_part) {
  const int bh = blockIdx.x >> 1;
  const int half = blockIdx.x & 1;
  const int w = threadIdx.x >> 6;
  const int seg = half * 4 + w;
  const int lane = threadIdx.x & 63;
  const int lm = lane & 15, lk = lane >> 4;
  const ushort* kp = kb + (size_t)bh * 32 * NTOK + (size_t)seg * 512;
  const ushort* vp = vb + (size_t)bh * 32 * NTOK + (size_t)seg * 512;
  f32x4 acc[2][2];
#pragma unroll
  for (int i = 0; i < 2; ++i)
#pragma unroll
    for (int j = 0; j < 2; ++j) acc[i][j] = (f32x4){0.f, 0.f, 0.f, 0.f};
#pragma unroll 4
  for (int ks = 0; ks < 16; ++ks) {
    const int coff = ks * 32 + lk * 8;
    const s16x8 a0 = *reinterpret_cast<const s16x8*>(kp + (size_t)lm * NTOK + coff);
    const s16x8 a1 = *reinterpret_cast<const s16x8*>(kp + (size_t)(16 + lm) * NTOK + coff);
    const s16x8 b0 = *reinterpret_cast<const s16x8*>(vp + (size_t)lm * NTOK + coff);
    const s16x8 b1 = *reinterpret_cast<const s16x8*>(vp + (size_t)(16 + lm) * NTOK + coff);
    acc[0][0] = __builtin_amdgcn_mfma_f32_16x16x32_bf16(a0, b0, acc[0][0], 0, 0, 0);
    acc[0][1] = __builtin_amdgcn_mfma_f32_16x16x32_bf16(a0, b1, acc[0][1], 0, 0, 0);
    acc[1][0] = __builtin_amdgcn_mfma_f32_16x16x32_bf16(a1, b0, acc[1][0], 0, 0, 0);
    acc[1][1] = __builtin_amdgcn_mfma_f32_16x16x32_bf16(a1, b1, acc[1][1], 0, 0, 0);
  }
  float* op = ctx_part + ((size_t)bh * 8 + seg) * 1024;
#pragma unroll
  for (int et = 0; et < 2; ++et)
#pragma unroll
    for (int dt = 0; dt < 2; ++dt)
#pragma unroll
      for (int r = 0; r < 4; ++r)
        op[(et * 16 + lk * 4 + r) * 32 + dt * 16 + lm] = acc[et][dt][r];
}

// ---------------------------------------------------------------------------
// K5: W2'[b][o][c'] = (sum_d w_out[o][h*32+d] * ctx[b][h][e][d]) * f[c'],
// f[c'] = SCALE / sum_n E[c'][n]. -> bf16. ctx sums 8 segment partials.
// ---------------------------------------------------------------------------
__global__ __launch_bounds__(256) void k_w2(const float* __restrict__ ctx_part,
                                            const float* __restrict__ spart,
                                            const float* __restrict__ w_out,
                                            ushort* __restrict__ W2b) {
  const int b = blockIdx.x;
  const int t = threadIdx.x;
  __shared__ float ctx[4096];
  __shared__ float fbuf[128];
#pragma unroll
  for (int i = 0; i < 16; ++i) {
    const int idx = t + 256 * i;
    const int h = idx >> 10, ed = idx & 1023;
    const float* cp = ctx_part + ((size_t)((b * 4 + h) * 8)) * 1024 + ed;
    float a = 0.f;
#pragma unroll
    for (int j = 0; j < 8; ++j) a += cp[j * 1024];
    ctx[idx] = a;
  }
  if (t < 128) {
    float s = 0.f;
    for (int p = 0; p < 64; ++p) s += spart[((size_t)b * 64 + p) * 128 + t];
    fbuf[t] = SCALE / s;
  }
  __syncthreads();
  const float* wrow = w_out + (size_t)t * 128;
  ushort* wout_row = W2b + ((size_t)b * 256 + t) * 128;
  float wv[32];
  for (int h = 0; h < 4; ++h) {
#pragma unroll
    for (int d = 0; d < 32; ++d) wv[d] = wrow[h * 32 + d];
#pragma unroll 4
    for (int e = 0; e < 32; ++e) {
      float a = 0.f;
#pragma unroll
      for (int d = 0; d < 32; ++d) a += wv[d] * ctx[h * 1024 + e * 32 + d];
      wout_row[h * 32 + e] = bf_rne(a * fbuf[h * 32 + e]);
    }
  }
}

// ---------------------------------------------------------------------------
// K6: out[b][o][n] = sum_c W2'[b][o][c] * E[b][c][n] + b_out[o], bf16 MFMA.
// BK=64, 2 iters. A via gl_lds (swizzled source), B gather staged.
// grid (32, 2, 32).  (at memory roofline: 134 MB fp32 output write)
// ---------------------------------------------------------------------------
__global__ __launch_bounds__(256) void k_out_mfma(const ushort* __restrict__ Ecn,
                                                  const ushort* __restrict__ W2b,
                                                  const float* __restrict__ b_out,
                                                  float* __restrict__ out) {
  const int n0 = blockIdx.x * 128;
  const int o0 = blockIdx.y * 128;
  const int b  = blockIdx.z;
  const ushort* A  = W2b + (size_t)b * 256 * 128;
  const ushort* Bq = Ecn + (size_t)b * 128 * NTOK;

  __shared__ ushort As[8192];
  __shared__ ushort Bt[8192];

  const int t = threadIdx.x;
  const int lane = t & 63;
  const int wv = t >> 6;
  const int wr = wv >> 1, wc = wv & 1;
  const int lm = lane & 15;
  const int lk = lane >> 4;

  int aoff[4][2], boff[4][2];
#pragma unroll
  for (int mf = 0; mf < 4; ++mf) {
    const int ar = wr * 64 + mf * 16 + lm;
#pragma unroll
    for (int ks = 0; ks < 2; ++ks)
      aoff[mf][ks] = ar * 64 + 8 * ((ks * 4 + lk) ^ (ar & 7));
  }
#pragma unroll
  for (int nf = 0; nf < 4; ++nf) {
    const int br = wc * 64 + nf * 16 + lm;
#pragma unroll
    for (int ks = 0; ks < 2; ++ks)
      boff[nf][ks] = br * 64 + 8 * ((ks * 4 + lk) ^ (br & 7));
  }
  size_t gaA[4];
  int lb[4];
#pragma unroll
  for (int i = 0; i < 4; ++i) {
    const int s_total = t + 256 * i;
    const int r = s_total >> 3;
    const int q = (s_total & 7) ^ (r & 7);
    gaA[i] = (size_t)(o0 + r) * 128 + q * 8;
    lb[i] = wv * 512 + i * 2048;
  }
  int bst[8], bn[8], bcg[8];
#pragma unroll
  for (int i = 0; i < 8; ++i) {
    const int u = t + 256 * i;
    bn[i] = u & 127;
    bcg[i] = u >> 7;
    bst[i] = bn[i] * 64 + 8 * ((bcg[i] >> 1) ^ (bn[i] & 7)) + (bcg[i] & 1) * 4;
  }

  f32x4 acc[4][4];
#pragma unroll
  for (int i = 0; i < 4; ++i)
#pragma unroll
    for (int j = 0; j < 4; ++j) acc[i][j] = (f32x4){0.f, 0.f, 0.f, 0.f};

  for (int it = 0; it < 2; ++it) {
    const size_t c0 = (size_t)it * 64;
    __syncthreads();
#pragma unroll
    for (int i = 0; i < 4; ++i)
      gl_lds16(A + gaA[i] + c0, As + lb[i]);
#pragma unroll
    for (int i = 0; i < 8; ++i) {
      const ushort* gp = Bq + (c0 + bcg[i] * 4) * NTOK + n0 + bn[i];
      ushort4 hvec;
      hvec.x = gp[0];
      hvec.y = gp[NTOK];
      hvec.z = gp[2 * NTOK];
      hvec.w = gp[3 * NTOK];
      *reinterpret_cast<ushort4*>(Bt + bst[i]) = hvec;
    }
    __syncthreads();
#pragma unroll
    for (int ks = 0; ks < 2; ++ks) {
      s16x8 af[4], bf[4];
#pragma unroll
      for (int mf = 0; mf < 4; ++mf)
        af[mf] = *reinterpret_cast<const s16x8*>(As + aoff[mf][ks]);
#pragma unroll
      for (int nf = 0; nf < 4; ++nf)
        bf[nf] = *reinterpret_cast<const s16x8*>(Bt + boff[nf][ks]);
#pragma unroll
      for (int mf = 0; mf < 4; ++mf)
#pragma unroll
        for (int nf = 0; nf < 4; ++nf)
          acc[mf][nf] = __builtin_amdgcn_mfma_f32_16x16x32_bf16(af[mf], bf[nf], acc[mf][nf], 0, 0, 0);
    }
  }

  float* C = out + ((size_t)b * 256 + o0) * NTOK + n0;
#pragma unroll
  for (int mf = 0; mf < 4; ++mf) {
    const int row0 = wr * 64 + mf * 16 + lk * 4;
#pragma unroll
    for (int nf = 0; nf < 4; ++nf) {
      const int col = wc * 64 + nf * 16 + lm;
#pragma unroll
      for (int r = 0; r < 4; ++r) {
        const float bias = b_out[o0 + row0 + r];
        C[(size_t)(row0 + r) * NTOK + col] = acc[mf][nf][r] + bias;
      }
    }
  }
}

extern "C" void kernel_launch(void* const* d_in, const int* in_sizes, int n_in,
                              void* d_out, int out_size, void* d_ws, size_t ws_size,
                              hipStream_t stream) {
  const float* x     = (const float*)d_in[0];
  const float* w_qkv = (const float*)d_in[1];
  const float* w_out = (const float*)d_in[2];
  const float* b_out = (const float*)d_in[3];
  float* out = (float*)d_out;

  ushort* kb  = (ushort*)d_ws;                          // 16777216 us (33.5MB)
  ushort* vb  = kb + (size_t)16777216;                  // 33.5MB
  ushort* Ecn = vb + (size_t)16777216;                  // 33.5MB
  float*  ctx_part = (float*)(Ecn + (size_t)16777216);  // 1048576 f32 (4MB)
  float*  spart    = ctx_part + 1048576;                // 262144 f32 (1MB)
  ushort* wb  = (ushort*)(spart + 262144);              // 98304 us
  ushort* W2b = wb + 98304;                             // 1048576 us (2MB)

  k_cvt_w<<<96, 256, 0, stream>>>(w_qkv, wb);
  k_qkv_mfma<<<dim3(32, 3, 32), 512, 0, stream>>>(x, wb, Ecn, kb, vb, spart);
  k_context_mfma<<<256, 256, 0, stream>>>(kb, vb, ctx_part);
  k_w2<<<32, 256, 0, stream>>>(ctx_part, spart, w_out, W2b);
  k_out_mfma<<<dim3(32, 2, 32), 256, 0, stream>>>(Ecn, W2b, b_out, out);
}